// Round 6
// baseline (1347.629 us; speedup 1.0000x reference)
//
#include <hip/hip_runtime.h>
#include <math.h>

#define HH 96
#define WWI 96
#define NN 9216        // H*W
#define CC 256
#define LL 9216
#define CHK 96
#define NCH 96
#define BB 8
#define BN (BB*NN)     // 73728

__device__ __forceinline__ float softplusf(float x){
    float e = expf(-fabsf(x));
    return fmaxf(x, 0.f) + log1pf(e);
}
__device__ __forceinline__ float sigmf(float x){ return 1.f / (1.f + expf(-x)); }

__device__ __forceinline__ float wredsum(float v){
    #pragma unroll
    for(int o = 32; o > 0; o >>= 1) v += __shfl_xor(v, o, 64);
    return v;
}

// paired reduction: s and q interleaved so the two shfl chains overlap
__device__ __forceinline__ void wredsum2(float& s, float& q){
    #pragma unroll
    for(int o = 32; o > 0; o >>= 1){
        s += __shfl_xor(s, o, 64);
        q += __shfl_xor(q, o, 64);
    }
}

// scan chunk -> spatial walk: n = base + j*step, j = 0..95 (within-chunk scan order)
__device__ __forceinline__ void chunk_walk(int g, int chunk, int& base, int& step){
    if(g == 0){ base = chunk * 96;        step = 1;   }
    else if(g == 1){ base = 9215 - chunk * 96; step = -1; }
    else if(g == 2){ base = chunk;        step = 96;  }
    else { base = 9215 - chunk;           step = -96; }
}

// ---------------- K1: per-row LN stats of x -> mrs (mean, rstd) ------------------
__global__ __launch_bounds__(256) void k_stats(const float* __restrict__ x,
                                               float* __restrict__ mrs){
    int wid = threadIdx.x >> 6, lane = threadIdx.x & 63;
    size_t row = (size_t)blockIdx.x * 4 + wid;
    float4 v = ((const float4*)(x + row * CC))[lane];
    float s = wredsum(v.x + v.y + v.z + v.w);
    float q = wredsum(v.x*v.x + v.y*v.y + v.z*v.z + v.w*v.w);
    float m = s * (1.f/256.f);
    float var = q * (1.f/256.f) - m*m;
    float rs = rsqrtf(fmaxf(var, 0.f) + 1e-5f);
    if(lane == 0){ mrs[2*row] = m; mrs[2*row+1] = rs; }
}

// ------------- K1c: fold final LN into proj weights --------------------------------
// Wn[o,k] = pw[o,k]*nw[k]; wsum[o] = sum_k Wn[o,k]; cvec[o] = sum_k pw[o,k]*nb[k] + pb[o]
__global__ __launch_bounds__(256) void k_prew(const float* __restrict__ pw,
        const float* __restrict__ nw, const float* __restrict__ nb,
        const float* __restrict__ pb, float* __restrict__ Wn,
        float* __restrict__ wsum, float* __restrict__ cvec){
    int o = threadIdx.x;
    float ws = 0.f, cc = 0.f;
    for(int k = 0; k < 256; k++){
        float w = pw[(size_t)o * 256 + k];
        float wn = w * nw[k];
        Wn[(size_t)o * 256 + k] = wn;
        ws += wn; cc += w * nb[k];
    }
    wsum[o] = ws; cvec[o] = cc + pb[o];
}

// ------------- K1d: fold x-LN into in_proj weights -------------------------------
// For each group g, out-channel o in [0,128):
//   Wip[(g*128+o)*64+k] = ipw[g,o,k]*nw[g*64+k]
//   wsip[g*128+o] = sum_k Wip;  cvip[g*128+o] = sum_k ipw*nb[g*64+k] + ipb[g,o]
__global__ __launch_bounds__(128) void k_prewip(const float* __restrict__ ipw,
        const float* __restrict__ nw, const float* __restrict__ nb,
        const float* __restrict__ ipb, float* __restrict__ Wip,
        float* __restrict__ wsip, float* __restrict__ cvip){
    int g = blockIdx.x, o = threadIdx.x;
    const float* wr = ipw + ((size_t)(g*128 + o)) * 64;
    float ws = 0.f, cc = 0.f;
    for(int k = 0; k < 64; k++){
        float w = wr[k];
        float wn = w * nw[g*64 + k];
        Wip[((size_t)(g*128 + o))*64 + k] = wn;
        ws += wn; cc += w * nb[g*64 + k];
    }
    wsip[g*128 + o] = ws;
    cvip[g*128 + o] = cc + ipb[g*128 + o];
}

// ---------------- K2: partial column sums of LN(x) -> zpart ----------------------
__global__ __launch_bounds__(256) void k_zavg(const float* __restrict__ x,
        const float* __restrict__ mrs, const float* __restrict__ nw,
        const float* __restrict__ nb, float* __restrict__ zpart){
    int c = threadIdx.x, b = blockIdx.y, t0 = blockIdx.x * 256;
    float nwv = nw[c], nbv = nb[c];
    float s = 0.f;
    for(int i = 0; i < 256; i++){
        size_t r = (size_t)b * NN + t0 + i;
        s += (x[r * CC + c] - mrs[2*r]) * mrs[2*r+1] * nwv + nbv;
    }
    zpart[((size_t)b * 36 + blockIdx.x) * CC + c] = s;
}

// ---------------- K3: gate = sigmoid(z@fc_w.T + fc_b + conv1d(z)) ----------------
__global__ __launch_bounds__(256) void k_gate(const float* __restrict__ zpart,
        const float* __restrict__ fcw, const float* __restrict__ fcb,
        const float* __restrict__ w1d, float* __restrict__ gate){
    __shared__ float za[CC];
    int c = threadIdx.x, b = blockIdx.x;
    float s = 0.f;
    for(int t = 0; t < 36; t++) s += zpart[((size_t)b * 36 + t) * CC + c];
    za[c] = s * (1.f/(float)NN);
    __syncthreads();
    float zm1 = (c > 0)     ? za[c-1] : 0.f;
    float zp1 = (c < CC-1)  ? za[c+1] : 0.f;
    float acc = fcb[c] + w1d[0]*zm1 + w1d[1]*za[c] + w1d[2]*zp1;
    const float* wr = fcw + (size_t)c * CC;
    for(int k = 0; k < CC; k++) acc += za[k] * wr[k];
    gate[b * CC + c] = sigmf(acc);
}

// ------ K4a2 (tier4): LN-folded full in_proj, LDS-free ---------------------------
// 256 thr, 16 rows/block, blockIdx.y = group-pair. Thread -> (g, half, c).
// Raw x rows read wave-uniform (L1 broadcast); LN folded into Wip/wsip/cvip.
// x-half -> xib, silu(z-half) -> zbuf (both group-major).
__global__ __launch_bounds__(256) void k_inproj2(const float* __restrict__ x,
        const float* __restrict__ mrs, const float* __restrict__ Wip,
        const float* __restrict__ wsip, const float* __restrict__ cvip,
        float* __restrict__ xib, float* __restrict__ zbuf){
    int t = threadIdx.x;
    int g = blockIdx.y * 2 + (t >> 7);   // waves 0,1 -> g0; waves 2,3 -> g1
    int h = (t >> 6) & 1;                // 0 = x-half, 1 = z-half
    int c = t & 63;
    int r0 = blockIdx.x * 16;            // global row base; NN%16==0 -> same b
    int b  = r0 / NN;
    int n0 = r0 - b * NN;
    int oc = g*128 + h*64 + c;
    float wv[64];
    {
        const float4* wr = (const float4*)(Wip + (size_t)oc * 64);
        #pragma unroll
        for(int j = 0; j < 16; j++){
            float4 t4 = wr[j];
            wv[4*j+0] = t4.x; wv[4*j+1] = t4.y;
            wv[4*j+2] = t4.z; wv[4*j+3] = t4.w;
        }
    }
    float acc[16];
    const float* ab = x + (size_t)r0 * CC + g * 64;
    #pragma unroll 4
    for(int r = 0; r < 16; r++){
        const float4* ar = (const float4*)(ab + (size_t)r * CC);  // wave-uniform
        float s0 = 0.f, s1 = 0.f;
        #pragma unroll
        for(int j = 0; j < 8; j++){
            float4 u = ar[j], v = ar[j + 8];
            s0 += u.x*wv[4*j+0]  + u.y*wv[4*j+1]  + u.z*wv[4*j+2]  + u.w*wv[4*j+3];
            s1 += v.x*wv[32+4*j] + v.y*wv[33+4*j] + v.z*wv[34+4*j] + v.w*wv[35+4*j];
        }
        acc[r] = s0 + s1;
    }
    float ws = wsip[oc], cv = cvip[oc];
    size_t obase = ((size_t)(b*4 + g)) * NN + n0;
    #pragma unroll
    for(int r = 0; r < 16; r++){
        size_t row = (size_t)r0 + r;
        float m = mrs[2*row], rs = mrs[2*row+1];
        float v = rs * acc[r] - m * rs * ws + cv;
        if(h == 0)
            xib[(obase + r)*64 + c] = v;
        else
            zbuf[(obase + r)*64 + c] = v * sigmf(v);
    }
}

// ------ K4a (tier3 fallback): LN + full in_proj per 128-pos tile -----------------
__global__ __launch_bounds__(256) void k_inproj(const float* __restrict__ x,
        const float* __restrict__ mrs, const float* __restrict__ nw,
        const float* __restrict__ nb, const float* __restrict__ ipw,
        const float* __restrict__ ipb, float* __restrict__ xib,
        float* __restrict__ zbuf){
    int tile = blockIdx.x, b = blockIdx.y, g = blockIdx.z;
    int n0 = tile * 128;
    __shared__ float xs[128 * 64];
    int tid = threadIdx.x;
    for(int idx = tid; idx < 2048; idx += 256){
        int p = idx >> 4, k4 = (idx & 15) * 4;
        size_t r = (size_t)b * NN + n0 + p;
        float4 v = *(const float4*)(x + r * CC + g*64 + k4);
        float m = mrs[2*r], rs = mrs[2*r+1];
        float4 w4 = *(const float4*)(nw + g*64 + k4);
        float4 b4 = *(const float4*)(nb + g*64 + k4);
        float4 o;
        o.x = (v.x - m)*rs*w4.x + b4.x;
        o.y = (v.y - m)*rs*w4.y + b4.y;
        o.z = (v.z - m)*rs*w4.z + b4.z;
        o.w = (v.w - m)*rs*w4.w + b4.w;
        *(float4*)(xs + p*64 + k4) = o;
    }
    __syncthreads();
    int c = tid & 63, ph = tid >> 6;   // channel c (both halves), position quarter
    float wx[64], wz[64];
    {
        const float* wrx = ipw + ((size_t)(g*128 + c)) * 64;
        const float* wrz = ipw + ((size_t)(g*128 + 64 + c)) * 64;
        #pragma unroll
        for(int k = 0; k < 64; k++){ wx[k] = wrx[k]; wz[k] = wrz[k]; }
    }
    float bx = ipb[g*128 + c], bz = ipb[g*128 + 64 + c];
    size_t obase = ((size_t)(b*4 + g)) * NN + n0;
    for(int p = ph*32; p < ph*32 + 32; p++){
        const float4* xp = (const float4*)(xs + p*64);
        float a0 = 0.f, a1 = 0.f, z0 = 0.f, z1 = 0.f;
        #pragma unroll
        for(int k4 = 0; k4 < 16; k4 += 2){
            float4 u = xp[k4], v = xp[k4+1];
            a0 += u.x*wx[4*k4+0]; a1 += u.y*wx[4*k4+1];
            a0 += u.z*wx[4*k4+2]; a1 += u.w*wx[4*k4+3];
            z0 += u.x*wz[4*k4+0]; z1 += u.y*wz[4*k4+1];
            z0 += u.z*wz[4*k4+2]; z1 += u.w*wz[4*k4+3];
            a0 += v.x*wx[4*k4+4]; a1 += v.y*wx[4*k4+5];
            a0 += v.z*wx[4*k4+6]; a1 += v.w*wx[4*k4+7];
            z0 += v.x*wz[4*k4+4]; z1 += v.y*wz[4*k4+5];
            z0 += v.z*wz[4*k4+6]; z1 += v.w*wz[4*k4+7];
        }
        float xv = bx + a0 + a1;
        float zv = bz + z0 + z1;
        xib[(obase + p)*64 + c] = xv;
        zbuf[(obase + p)*64 + c] = zv * sigmf(zv);
    }
}

// ------ K4b (tier3): depthwise conv3x3 + silu, halo from global xi ---------------
__global__ __launch_bounds__(256) void k_conv(const float* __restrict__ xib,
        const float* __restrict__ cw, const float* __restrict__ cb,
        float* __restrict__ out){
    int tile = blockIdx.x, b = blockIdx.y, g = blockIdx.z;
    int h0 = (tile/12)*8, w0 = (tile%12)*8;
    __shared__ float xs[100*64];
    int tid = threadIdx.x;
    size_t ibase = ((size_t)(b*4+g)) * NN;
    for(int i = tid; i < 6400; i += 256){
        int p = i >> 6, k = i & 63;
        int ph = h0 + p/10 - 1, pw = w0 + p%10 - 1;
        float v = 0.f;
        if(ph >= 0 && ph < HH && pw >= 0 && pw < WWI)
            v = xib[(ibase + (size_t)(ph*WWI + pw))*64 + k];
        xs[i] = v;
    }
    __syncthreads();
    int c = tid & 63, q = tid >> 6;
    float wk[9];
    const float* wp = cw + ((size_t)(g*64 + c))*9;
    #pragma unroll
    for(int j = 0; j < 9; j++) wk[j] = wp[j];
    float bias2 = cb[g*64 + c];
    for(int pi = q*16; pi < q*16+16; pi++){
        int py = pi >> 3, px = pi & 7;
        float acc = bias2;
        #pragma unroll
        for(int dy = 0; dy < 3; dy++)
            #pragma unroll
            for(int dx = 0; dx < 3; dx++)
                acc += xs[((py+dy)*10 + px+dx)*64 + c] * wk[dy*3+dx];
        float sv = acc * sigmf(acc);
        size_t r = (size_t)b*NN + (h0+py)*WWI + (w0+px);
        out[r*CC + g*64 + c] = sv;
    }
}

// ------ K4 (fallback): fused LN + in_proj(x half) + depthwise conv3x3 + silu -----
template<int ZPRE>
__global__ __launch_bounds__(256) void k_ipconv(const float* __restrict__ x,
        const float* __restrict__ mrs, const float* __restrict__ nw,
        const float* __restrict__ nb, const float* __restrict__ ipw,
        const float* __restrict__ ipb, const float* __restrict__ cw,
        const float* __restrict__ cb, float* __restrict__ out,
        float* __restrict__ zbuf){
    int tile = blockIdx.x, b = blockIdx.y, g = blockIdx.z;
    int h0 = (tile / 12) * 8, w0 = (tile % 12) * 8;
    __shared__ float xs[100 * 64];
    __shared__ float xi[100 * 64];
    int tid = threadIdx.x;
    for(int i = tid; i < 6400; i += 256){
        int p = i >> 6, k = i & 63;
        int ph = h0 + p / 10 - 1, pw = w0 + p % 10 - 1;
        float v = 0.f;
        if(ph >= 0 && ph < HH && pw >= 0 && pw < WWI){
            size_t r = (size_t)b * NN + ph * WWI + pw;
            v = (x[r * CC + g*64 + k] - mrs[2*r]) * mrs[2*r+1]
                * nw[g*64 + k] + nb[g*64 + k];
        }
        xs[i] = v;
    }
    __syncthreads();
    int c = tid & 63, q = tid >> 6;
    {
        float wv[64];
        const float* wr = ipw + ((size_t)(g * 128 + c)) * 64;
        #pragma unroll
        for(int k = 0; k < 64; k++) wv[k] = wr[k];
        float bias = ipb[g * 128 + c];
        for(int p = q * 25; p < q * 25 + 25; p++){
            int ph = h0 + p / 10 - 1, pw = w0 + p % 10 - 1;
            bool valid = (ph >= 0 && ph < HH && pw >= 0 && pw < WWI);
            float acc = bias;
            const float* xp = &xs[p * 64];
            #pragma unroll
            for(int k = 0; k < 64; k++) acc += xp[k] * wv[k];
            xi[p * 64 + c] = valid ? acc : 0.f;   // conv zero-pads AFTER in_proj
        }
    }
    __syncthreads();
    float wk[9];
    const float* wp = cw + ((size_t)(g * 64 + c)) * 9;
    #pragma unroll
    for(int j = 0; j < 9; j++) wk[j] = wp[j];
    float bias2 = cb[g * 64 + c];
    for(int pi = q * 16; pi < q * 16 + 16; pi++){
        int py = pi >> 3, px = pi & 7;
        float acc = bias2;
        #pragma unroll
        for(int dy = 0; dy < 3; dy++)
            #pragma unroll
            for(int dx = 0; dx < 3; dx++)
                acc += xi[((py + dy) * 10 + px + dx) * 64 + c] * wk[dy*3 + dx];
        float sv = acc * sigmf(acc);
        size_t r = (size_t)b * NN + (h0 + py) * WWI + (w0 + px);
        out[r * CC + g*64 + c] = sv;
    }
    if(ZPRE){
        float wzv[64];
        const float* wr = ipw + ((size_t)(g * 128 + 64 + c)) * 64;
        #pragma unroll
        for(int k = 0; k < 64; k++) wzv[k] = wr[k];
        float zbv = ipb[g * 128 + 64 + c];
        size_t zb0 = ((size_t)(b * 4 + g)) * NN;
        for(int p16 = 0; p16 < 16; p16++){
            int p = q * 16 + p16;
            int py = p >> 3, px = p & 7;
            const float* xp = &xs[((py + 1) * 10 + (px + 1)) * 64];
            float acc = zbv;
            #pragma unroll
            for(int k = 0; k < 64; k++) acc += xp[k] * wzv[k];
            zbuf[(zb0 + (size_t)((h0 + py) * WWI + (w0 + px))) * 64 + c]
                = acc * sigmf(acc);
        }
    }
}

// ---------------- K5: scan phase 1 — on-the-fly xdbl, prod(a), h_end -------------
__global__ __launch_bounds__(64) void k_scan1(const float* __restrict__ out,
        const float* __restrict__ xpw, const float* __restrict__ dtw,
        const float* __restrict__ dtb, const float* __restrict__ alog,
        float* __restrict__ ap_out, float* __restrict__ h_out){
    int chunk = blockIdx.x, gb = blockIdx.y;
    int g = gb >> 3, b = gb & 7, d = threadIdx.x;
    __shared__ float s_seq[CHK * 65];
    __shared__ float s_xd[CHK * 6];
    __shared__ float s_w[6 * 64];
    int base, step; chunk_walk(g, chunk, base, step);
    const float* xg = out + (size_t)b * NN * CC + g * 64;
    for(int j = 0; j < CHK; j++)
        s_seq[j * 65 + d] = xg[(size_t)(base + j * step) * CC + d];
    for(int i = d; i < 384; i += 64) s_w[i] = xpw[g * 384 + i];
    __syncthreads();
    for(int idx = d; idx < CHK*6; idx += 64){
        int l = idx / 6, j = idx % 6;
        float acc = 0.f;
        const float* sr = &s_seq[l * 65];
        const float* wr = &s_w[j * 64];
        #pragma unroll
        for(int k = 0; k < 64; k++) acc += sr[k] * wr[k];
        s_xd[idx] = acc;
    }
    __syncthreads();
    int gd = g * 64 + d;
    float Av = -expf(alog[gd]);
    float db = dtb[gd];
    float w0 = dtw[gd*4], w1 = dtw[gd*4+1], w2 = dtw[gd*4+2], w3 = dtw[gd*4+3];
    float h = 0.f, apd = 1.f;
    #pragma unroll 4
    for(int l = 0; l < CHK; l++){
        const float* xd = &s_xd[l * 6];
        float xv = s_seq[l*65 + d];
        float dt = softplusf(xd[0]*w0 + xd[1]*w1 + xd[2]*w2 + xd[3]*w3 + db);
        float a = expf(dt * Av);
        h = a*h + dt*xv*xd[4];
        apd *= a;
    }
    int ob = (gb * NCH + chunk) * 64 + d;
    ap_out[ob] = apd; h_out[ob] = h;
}

// ---------------- K6: scan phase 2 — serial scan over chunk summaries ------------
__global__ __launch_bounds__(256) void k_scan2(const float* __restrict__ ap,
        const float* __restrict__ he, float* __restrict__ hinit){
    int idx = blockIdx.x * 256 + threadIdx.x;   // 0..2047
    int gb = idx >> 6, d = idx & 63;
    float h = 0.f;
    for(int c = 0; c < NCH; c++){
        int o = (gb * NCH + c) * 64 + d;
        hinit[o] = h;
        h = ap[o]*h + he[o];
    }
}

// --- K7: scan phase 3 + out_norm LN + silu(z) gate, IN PLACE ---------------------
template<int ZPRE>
__global__ __launch_bounds__(64) void k_scan3(float* __restrict__ out,
        const float* __restrict__ x, const float* __restrict__ mrs,
        const float* __restrict__ nw, const float* __restrict__ nb,
        const float* __restrict__ ipw, const float* __restrict__ ipb,
        const float* __restrict__ xpw, const float* __restrict__ dtw,
        const float* __restrict__ dtb, const float* __restrict__ alog,
        const float* __restrict__ Dsp, const float* __restrict__ onw,
        const float* __restrict__ onb, const float* __restrict__ hinit,
        const float* __restrict__ zbuf){
    int chunk = blockIdx.x, gb = blockIdx.y;
    int g = gb >> 3, b = gb & 7, d = threadIdx.x;
    __shared__ float s_seq[CHK * 65];          // seq, then y (overwritten in place)
    __shared__ float s_xd[CHK * 6];
    __shared__ float s_w[6 * 64];
    __shared__ float xnt[(ZPRE ? 1 : CHK) * 65];
    int base, step; chunk_walk(g, chunk, base, step);
    float* xg = out + (size_t)b * NN * CC + g * 64;
    for(int j = 0; j < CHK; j++)
        s_seq[j * 65 + d] = xg[(size_t)(base + j * step) * CC + d];
    if(!ZPRE){
        float nwv = nw[g*64 + d], nbv = nb[g*64 + d];
        for(int j = 0; j < CHK; j++){
            int n = base + j * step;
            size_t r = (size_t)b * NN + n;
            xnt[j * 65 + d] = (x[r * CC + g*64 + d] - mrs[2*r]) * mrs[2*r+1] * nwv + nbv;
        }
    }
    for(int i = d; i < 384; i += 64) s_w[i] = xpw[g * 384 + i];
    __syncthreads();
    for(int idx = d; idx < CHK*6; idx += 64){
        int l = idx / 6, j = idx % 6;
        float acc = 0.f;
        const float* sr = &s_seq[l * 65];
        const float* wr = &s_w[j * 64];
        #pragma unroll
        for(int k = 0; k < 64; k++) acc += sr[k] * wr[k];
        s_xd[idx] = acc;
    }
    __syncthreads();
    int gd = g * 64 + d;
    float Av = -expf(alog[gd]);
    float db = dtb[gd];
    float Dv = Dsp[gd];
    float w0 = dtw[gd*4], w1 = dtw[gd*4+1], w2 = dtw[gd*4+2], w3 = dtw[gd*4+3];
    float h = hinit[(gb * NCH + chunk) * 64 + d];
    // ---- Phase A: scan. Only h is loop-carried; y overwrites s_seq row. ----
    #pragma unroll 4
    for(int l = 0; l < CHK; l++){
        const float* xd = &s_xd[l * 6];
        float xv = s_seq[l*65 + d];
        float dt = softplusf(xd[0]*w0 + xd[1]*w1 + xd[2]*w2 + xd[3]*w3 + db);
        float a = expf(dt * Av);
        h = a*h + dt*xv*xd[4];
        s_seq[l*65 + d] = h * xd[5] + Dv * xv;
    }
    // ---- Phase B: out_norm LN + silu(z) gate. Iterations independent. ----
    float wON = onw[gd], bON = onb[gd];
    float wz[ZPRE ? 1 : 64];
    float zb = 0.f;
    if(!ZPRE){
        const float* wr = ipw + ((size_t)(g * 128 + 64 + d)) * 64;
        #pragma unroll
        for(int k = 0; k < 64; k++) wz[k] = wr[k];
        zb = ipb[g * 128 + 64 + d];
    }
    const float* zp = zbuf + (((size_t)(b * 4 + g)) * NN) * 64 + d;
    #pragma unroll 4
    for(int l = 0; l < CHK; l++){
        float y = s_seq[l*65 + d];
        float s = y, q = y * y;
        wredsum2(s, q);
        float m = s * (1.f/64.f);
        float var = q * (1.f/64.f) - m*m;
        float rs = rsqrtf(fmaxf(var, 0.f) + 1e-5f);
        float lny = (y - m) * rs * wON + bON;
        int n = base + l * step;
        float zs;
        if(ZPRE){
            zs = zp[(size_t)n * 64];
        } else {
            float z = zb;
            const float* xp = &xnt[l * 65];
            #pragma unroll
            for(int k = 0; k < 64; k++) z += xp[k] * wz[k];
            zs = z * sigmf(z);
        }
        xg[(size_t)n * CC + d] = lny * zs;   // in-place (own tile)
    }
}

// --- K8 (fallback): out_proj + skip*xn*gate, spatial tiles, IN PLACE -------------
__global__ __launch_bounds__(64) void k_out2(float* __restrict__ out,
        const float* __restrict__ x, const float* __restrict__ mrs,
        const float* __restrict__ nw, const float* __restrict__ nb,
        const float* __restrict__ opw, const float* __restrict__ opb,
        const float* __restrict__ gate, const float* __restrict__ skip){
    int tile = blockIdx.x, b = blockIdx.y, g = blockIdx.z;
    int n0 = tile * 64, t = threadIdx.x;
    __shared__ float ly[64 * 65];
    __shared__ float xnt[64 * 65];
    float* xg = out + (size_t)b * NN * CC + g * 64;
    float nwv = nw[g*64 + t], nbv = nb[g*64 + t];
    for(int p = 0; p < 64; p++){
        size_t r = (size_t)b * NN + n0 + p;
        ly[p * 65 + t] = xg[(size_t)(n0 + p) * CC + t];
        xnt[p * 65 + t] = (x[r * CC + g*64 + t] - mrs[2*r]) * mrs[2*r+1] * nwv + nbv;
    }
    __syncthreads();
    float wv[64];
    const float* wr = opw + ((size_t)(g * 64 + t)) * 64;
    #pragma unroll
    for(int k = 0; k < 64; k++) wv[k] = wr[k];
    float bias = opb[g * 64 + t];
    float gv = gate[b * CC + g*64 + t];
    float sk = skip[0];
    for(int p = 0; p < 64; p++){
        float acc = bias;
        const float* yp = &ly[p * 65];
        #pragma unroll
        for(int k = 0; k < 64; k++) acc += yp[k] * wv[k];
        xg[(size_t)(n0 + p) * CC + t] = acc * sk * xnt[p * 65 + t] * gv;
    }
}

// --- K8new: out_proj + skip*xn*gate + fused row-stats, LDS-free ------------------
__global__ __launch_bounds__(256) void k_out3(const float* __restrict__ yin,
        const float* __restrict__ x, const float* __restrict__ mrs,
        const float* __restrict__ nw, const float* __restrict__ nb,
        const float* __restrict__ opw, const float* __restrict__ opb,
        const float* __restrict__ gate, const float* __restrict__ skip,
        float* __restrict__ zo, float* __restrict__ mrs2){
    __shared__ float ps[16 * 4], pq[16 * 4];
    int o = threadIdx.x;
    int g = o >> 6, c = o & 63;
    int r0 = blockIdx.x * 16;           // 16 rows/block; NN%16==0 -> same b
    int b  = r0 / NN;
    int n0 = r0 - b * NN;
    float wv[64];
    {
        const float4* wr = (const float4*)(opw + ((size_t)(g*64 + c)) * 64);
        #pragma unroll
        for(int j = 0; j < 16; j++){
            float4 t4 = wr[j];
            wv[4*j+0] = t4.x; wv[4*j+1] = t4.y;
            wv[4*j+2] = t4.z; wv[4*j+3] = t4.w;
        }
    }
    float acc[16];
    const float* ab = yin + ((size_t)b * NN + n0) * CC + g * 64;
    #pragma unroll 4
    for(int r = 0; r < 16; r++){
        const float4* ar = (const float4*)(ab + (size_t)r * CC);  // wave-uniform
        float s0 = 0.f, s1 = 0.f;
        #pragma unroll
        for(int j = 0; j < 8; j++){
            float4 u = ar[j], v = ar[j + 8];
            s0 += u.x*wv[4*j+0]  + u.y*wv[4*j+1]  + u.z*wv[4*j+2]  + u.w*wv[4*j+3];
            s1 += v.x*wv[32+4*j] + v.y*wv[33+4*j] + v.z*wv[34+4*j] + v.w*wv[35+4*j];
        }
        acc[r] = s0 + s1;
    }
    float bias = opb[g*64 + c];
    float gv = gate[b * CC + g*64 + c];
    float sk = skip[0];
    float nwv = nw[g*64 + c], nbv = nb[g*64 + c];
    size_t zbase = ((size_t)(b*4 + g)) * NN + n0;
    #pragma unroll
    for(int r = 0; r < 16; r++){
        size_t row = (size_t)r0 + r;
        float xv = x[row * CC + g*64 + c];           // per-lane coalesced
        float xn = (xv - mrs[2*row]) * mrs[2*row+1] * nwv + nbv;
        float res = (acc[r] + bias) * sk * xn * gv;
        acc[r] = res;
        zo[(zbase + r) * 64 + c] = res;
    }
    // fused row stats over 256 channels (64 lanes x 4 waves)
    #pragma unroll
    for(int r = 0; r < 16; r++){
        float s = acc[r], q = acc[r] * acc[r];
        wredsum2(s, q);
        if(c == 0){ ps[r*4 + g] = s; pq[r*4 + g] = q; }
    }
    __syncthreads();
    if(o < 16){
        float ss = ps[o*4] + ps[o*4+1] + ps[o*4+2] + ps[o*4+3];
        float qq = pq[o*4] + pq[o*4+1] + pq[o*4+2] + pq[o*4+3];
        float m = ss * (1.f/256.f);
        float var = qq * (1.f/256.f) - m*m;
        mrs2[2*((size_t)r0 + o)]     = m;
        mrs2[2*((size_t)r0 + o) + 1] = rsqrtf(fmaxf(var, 0.f) + 1e-5f);
    }
}

// ---------------- K9 (fallback): final LN + proj GEMM, IN PLACE ------------------
__global__ __launch_bounds__(256) void k_final(float* __restrict__ out,
        const float* __restrict__ nw, const float* __restrict__ nb,
        const float* __restrict__ pw, const float* __restrict__ pb){
    __shared__ float A[16 * 256];
    __shared__ float ps[256], pq[256];
    __shared__ float mrow[16], rrow[16];
    int n0 = blockIdx.x * 16;
    for(int i = threadIdx.x; i < 4096; i += 256)
        A[i] = out[(size_t)n0 * CC + i];
    __syncthreads();
    {
        int r = threadIdx.x >> 4, t16 = threadIdx.x & 15;
        float s = 0.f, q = 0.f;
        for(int j = 0; j < 16; j++){
            float v = A[r*256 + t16*16 + j];
            s += v; q += v*v;
        }
        ps[threadIdx.x] = s; pq[threadIdx.x] = q;
    }
    __syncthreads();
    if(threadIdx.x < 16){
        float ss = 0.f, qq = 0.f;
        for(int j = 0; j < 16; j++){ ss += ps[threadIdx.x*16 + j]; qq += pq[threadIdx.x*16 + j]; }
        float m = ss * (1.f/256.f);
        float var = qq * (1.f/256.f) - m*m;
        mrow[threadIdx.x] = m;
        rrow[threadIdx.x] = rsqrtf(fmaxf(var, 0.f) + 1e-5f);
    }
    __syncthreads();
    for(int i = threadIdx.x; i < 4096; i += 256){
        int r = i >> 8, c = i & 255;
        A[i] = (A[i] - mrow[r]) * rrow[r] * nw[c] + nb[c];
    }
    __syncthreads();
    int o = threadIdx.x;
    float acc[16];
    #pragma unroll
    for(int p = 0; p < 16; p++) acc[p] = 0.f;
    for(int kt = 0; kt < 4; kt++){
        float wv[64];
        const float4* wr = (const float4*)(pw + (size_t)o * CC + kt * 64);
        #pragma unroll
        for(int j = 0; j < 16; j++){
            float4 tq = wr[j];
            wv[4*j+0] = tq.x; wv[4*j+1] = tq.y;
            wv[4*j+2] = tq.z; wv[4*j+3] = tq.w;
        }
        #pragma unroll
        for(int p = 0; p < 16; p++){
            const float* ar = &A[p*256 + kt*64];
            float a = 0.f;
            #pragma unroll
            for(int k = 0; k < 64; k++) a += ar[k] * wv[k];
            acc[p] += a;
        }
    }
    float pbv = pb[o];
    #pragma unroll
    for(int p = 0; p < 16; p++)
        out[(size_t)(n0 + p) * CC + o] = acc[p] + pbv;
}

// ---------------- K9new: LN-folded proj GEMM, LDS-free ---------------------------
__global__ __launch_bounds__(256) void k_final2(const float* __restrict__ y,
        const float* __restrict__ mrs2, const float* __restrict__ Wn,
        const float* __restrict__ wsum, const float* __restrict__ cvec,
        float* __restrict__ out){
    int o = threadIdx.x;
    int r0 = blockIdx.x * 16;           // global row base (16 rows/block)
    int b  = r0 / NN;
    int n0 = r0 - b * NN;               // NN divisible by 16: all rows same b
    float acc[16];
    #pragma unroll
    for(int r = 0; r < 16; r++) acc[r] = 0.f;
    for(int kt = 0; kt < 4; kt++){
        float wv[64];
        const float4* wr = (const float4*)(Wn + (size_t)o * 256 + kt * 64);
        #pragma unroll
        for(int j = 0; j < 16; j++){
            float4 t4 = wr[j];
            wv[4*j+0] = t4.x; wv[4*j+1] = t4.y;
            wv[4*j+2] = t4.z; wv[4*j+3] = t4.w;
        }
        const float* ab = y + ((size_t)(b*4 + kt)*NN + n0) * 64;
        #pragma unroll 4
        for(int r = 0; r < 16; r++){
            const float* ar = ab + (size_t)r * 64;   // wave-uniform address
            float s0 = 0.f, s1 = 0.f;
            #pragma unroll
            for(int j = 0; j < 32; j++){
                s0 += ar[j]      * wv[j];
                s1 += ar[j + 32] * wv[j + 32];
            }
            acc[r] += s0 + s1;
        }
    }
    float wso = wsum[o], co = cvec[o];
    #pragma unroll
    for(int r = 0; r < 16; r++){
        float m  = mrs2[2*(size_t)(r0 + r)];
        float rs = mrs2[2*(size_t)(r0 + r) + 1];
        out[(size_t)(r0 + r) * CC + o] = rs * acc[r] - m * rs * wso + co;
    }
}

extern "C" void kernel_launch(void* const* d_in, const int* in_sizes, int n_in,
                              void* d_out, int out_size, void* d_ws, size_t ws_size,
                              hipStream_t stream){
    const float* x    = (const float*)d_in[0];
    const float* nw   = (const float*)d_in[1];
    const float* nb   = (const float*)d_in[2];
    const float* fcw  = (const float*)d_in[3];
    const float* fcb  = (const float*)d_in[4];
    const float* w1d  = (const float*)d_in[5];
    const float* ipw  = (const float*)d_in[6];
    const float* ipb  = (const float*)d_in[7];
    const float* cw   = (const float*)d_in[8];
    const float* cb   = (const float*)d_in[9];
    const float* xpw  = (const float*)d_in[10];
    const float* dtw  = (const float*)d_in[11];
    const float* dtb  = (const float*)d_in[12];
    const float* alog = (const float*)d_in[13];
    const float* Dsp  = (const float*)d_in[14];
    const float* onw  = (const float*)d_in[15];
    const float* onb  = (const float*)d_in[16];
    const float* opw  = (const float*)d_in[17];
    const float* opb  = (const float*)d_in[18];
    const float* pw   = (const float*)d_in[19];
    const float* pb   = (const float*)d_in[20];
    const float* skip = (const float*)d_in[21];

    // Workspace layout:
    //   base 2,957,312 | zbuf 75,497,472 | mrs2 589,824 | Wn 262,144
    //   | wsum 1,024 | cvec 1,024   -> T2 = 79,308,800
    //   | xib 75,497,472            -> T3 = 154,806,272
    //   | Wip 131,072 | wsip 2,048 | cvip 2,048 -> T4 = 154,941,440
    char* base = (char*)d_ws;
    float* mrs  = (float*)base;                      //   589,824 B
    float* gate = (float*)(base +  589824ull);       //     8,192 B
    float* ap   = (float*)(base +  598016ull);       //   786,432 B (zpart aliases)
    float* he   = (float*)(base + 1384448ull);       //   786,432 B
    float* hi   = (float*)(base + 2170880ull);       //   786,432 B
    float* zbuf = (float*)(base + 2957312ull);       //  75,497,472 B
    float* mrs2 = (float*)(base + 78454784ull);      //   589,824 B
    float* Wn   = (float*)(base + 79044608ull);      //   262,144 B
    float* wsum = (float*)(base + 79306752ull);      //     1,024 B
    float* cvec = (float*)(base + 79307776ull);      //     1,024 B
    float* xib  = (float*)(base + 79308800ull);      //  75,497,472 B
    float* Wip  = (float*)(base + 154806272ull);     //   131,072 B
    float* wsip = (float*)(base + 154937344ull);     //     2,048 B
    float* cvip = (float*)(base + 154939392ull);     //     2,048 B
    float* zpart = ap;                               // dead before k_scan1 writes ap
    float* out  = (float*)d_out;                     // spatial (B,N,256) scratch
    (void)in_sizes; (void)n_in; (void)out_size;

    const size_t T1 = 78454784ull;    // base + zbuf
    const size_t T2 = 79308800ull;    // + mrs2 + Wn + wsum + cvec
    const size_t T3 = 154806272ull;   // + xib
    const size_t T4 = 154941440ull;   // + Wip + wsip + cvip
    bool usez    = ws_size >= T1;
    bool usef2   = ws_size >= T2;
    bool usesplit= ws_size >= T3;
    bool useip2  = ws_size >= T4;

    if(usef2)
        k_prew<<<1, 256, 0, stream>>>(pw, nw, nb, pb, Wn, wsum, cvec);
    if(useip2)
        k_prewip<<<4, 128, 0, stream>>>(ipw, nw, nb, ipb, Wip, wsip, cvip);
    k_stats <<<18432, 256, 0, stream>>>(x, mrs);
    k_zavg  <<<dim3(36, 8), 256, 0, stream>>>(x, mrs, nw, nb, zpart);
    k_gate  <<<8, 256, 0, stream>>>(zpart, fcw, fcb, w1d, gate);
    if(useip2){
        k_inproj2<<<dim3(4608, 2), 256, 0, stream>>>(x, mrs, Wip, wsip, cvip,
                                                     xib, zbuf);
        k_conv  <<<dim3(144, 8, 4), 256, 0, stream>>>(xib, cw, cb, out);
    } else if(usesplit){
        k_inproj<<<dim3(72, 8, 4), 256, 0, stream>>>(x, mrs, nw, nb, ipw, ipb,
                                                     xib, zbuf);
        k_conv  <<<dim3(144, 8, 4), 256, 0, stream>>>(xib, cw, cb, out);
    } else if(usez){
        k_ipconv<1><<<dim3(144, 8, 4), 256, 0, stream>>>(x, mrs, nw, nb, ipw, ipb,
                                                         cw, cb, out, zbuf);
    } else {
        k_ipconv<0><<<dim3(144, 8, 4), 256, 0, stream>>>(x, mrs, nw, nb, ipw, ipb,
                                                         cw, cb, out, zbuf);
    }
    k_scan1 <<<dim3(96, 32), 64, 0, stream>>>(out, xpw, dtw, dtb, alog, ap, he);
    k_scan2 <<<8, 256, 0, stream>>>(ap, he, hi);
    if(usez){
        k_scan3<1><<<dim3(96, 32), 64, 0, stream>>>(out, x, mrs, nw, nb, ipw, ipb,
                                                    xpw, dtw, dtb, alog, Dsp, onw,
                                                    onb, hi, zbuf);
    } else {
        k_scan3<0><<<dim3(96, 32), 64, 0, stream>>>(out, x, mrs, nw, nb, ipw, ipb,
                                                    xpw, dtw, dtb, alog, Dsp, onw,
                                                    onb, hi, zbuf);
    }
    if(usef2){
        k_out3  <<<4608, 256, 0, stream>>>(out, x, mrs, nw, nb, opw, opb,
                                           gate, skip, zbuf, mrs2);
        k_final2<<<4608, 256, 0, stream>>>(zbuf, mrs2, Wn, wsum, cvec, out);
    } else {
        k_out2  <<<dim3(144, 8, 4), 64, 0, stream>>>(out, x, mrs, nw, nb, opw, opb,
                                                     gate, skip);
        k_final <<<4608, 256, 0, stream>>>(out, nw, nb, pw, pb);
    }
}

// Round 7
// 1227.705 us; speedup vs baseline: 1.0977x; 1.0977x over previous
//
#include <hip/hip_runtime.h>
#include <math.h>

#define HH 96
#define WWI 96
#define NN 9216        // H*W
#define CC 256
#define LL 9216
#define CHK 96
#define NCH 96
#define BB 8
#define BN (BB*NN)     // 73728

__device__ __forceinline__ float softplusf(float x){
    float e = expf(-fabsf(x));
    return fmaxf(x, 0.f) + log1pf(e);
}
__device__ __forceinline__ float sigmf(float x){ return 1.f / (1.f + expf(-x)); }

__device__ __forceinline__ float wredsum(float v){
    #pragma unroll
    for(int o = 32; o > 0; o >>= 1) v += __shfl_xor(v, o, 64);
    return v;
}

// paired reduction: s and q interleaved so the two shfl chains overlap
__device__ __forceinline__ void wredsum2(float& s, float& q){
    #pragma unroll
    for(int o = 32; o > 0; o >>= 1){
        s += __shfl_xor(s, o, 64);
        q += __shfl_xor(q, o, 64);
    }
}

// scan chunk -> spatial walk: n = base + j*step, j = 0..95 (within-chunk scan order)
__device__ __forceinline__ void chunk_walk(int g, int chunk, int& base, int& step){
    if(g == 0){ base = chunk * 96;        step = 1;   }
    else if(g == 1){ base = 9215 - chunk * 96; step = -1; }
    else if(g == 2){ base = chunk;        step = 96;  }
    else { base = 9215 - chunk;           step = -96; }
}

// ---------------- K1: per-row LN stats of x -> mrs (mean, rstd) ------------------
__global__ __launch_bounds__(256) void k_stats(const float* __restrict__ x,
                                               float* __restrict__ mrs){
    int wid = threadIdx.x >> 6, lane = threadIdx.x & 63;
    size_t row = (size_t)blockIdx.x * 4 + wid;
    float4 v = ((const float4*)(x + row * CC))[lane];
    float s = wredsum(v.x + v.y + v.z + v.w);
    float q = wredsum(v.x*v.x + v.y*v.y + v.z*v.z + v.w*v.w);
    float m = s * (1.f/256.f);
    float var = q * (1.f/256.f) - m*m;
    float rs = rsqrtf(fmaxf(var, 0.f) + 1e-5f);
    if(lane == 0){ mrs[2*row] = m; mrs[2*row+1] = rs; }
}

// ------------- K1c: fold final LN into proj weights --------------------------------
// Wn[o,k] = pw[o,k]*nw[k]; wsum[o] = sum_k Wn[o,k]; cvec[o] = sum_k pw[o,k]*nb[k] + pb[o]
__global__ __launch_bounds__(256) void k_prew(const float* __restrict__ pw,
        const float* __restrict__ nw, const float* __restrict__ nb,
        const float* __restrict__ pb, float* __restrict__ Wn,
        float* __restrict__ wsum, float* __restrict__ cvec){
    int o = threadIdx.x;
    float ws = 0.f, cc = 0.f;
    for(int k = 0; k < 256; k++){
        float w = pw[(size_t)o * 256 + k];
        float wn = w * nw[k];
        Wn[(size_t)o * 256 + k] = wn;
        ws += wn; cc += w * nb[k];
    }
    wsum[o] = ws; cvec[o] = cc + pb[o];
}

// ---------------- K2: partial column sums of LN(x) -> zpart ----------------------
__global__ __launch_bounds__(256) void k_zavg(const float* __restrict__ x,
        const float* __restrict__ mrs, const float* __restrict__ nw,
        const float* __restrict__ nb, float* __restrict__ zpart){
    int c = threadIdx.x, b = blockIdx.y, t0 = blockIdx.x * 256;
    float nwv = nw[c], nbv = nb[c];
    float s = 0.f;
    for(int i = 0; i < 256; i++){
        size_t r = (size_t)b * NN + t0 + i;
        s += (x[r * CC + c] - mrs[2*r]) * mrs[2*r+1] * nwv + nbv;
    }
    zpart[((size_t)b * 36 + blockIdx.x) * CC + c] = s;
}

// ---------------- K3: gate = sigmoid(z@fc_w.T + fc_b + conv1d(z)) ----------------
__global__ __launch_bounds__(256) void k_gate(const float* __restrict__ zpart,
        const float* __restrict__ fcw, const float* __restrict__ fcb,
        const float* __restrict__ w1d, float* __restrict__ gate){
    __shared__ float za[CC];
    int c = threadIdx.x, b = blockIdx.x;
    float s = 0.f;
    for(int t = 0; t < 36; t++) s += zpart[((size_t)b * 36 + t) * CC + c];
    za[c] = s * (1.f/(float)NN);
    __syncthreads();
    float zm1 = (c > 0)     ? za[c-1] : 0.f;
    float zp1 = (c < CC-1)  ? za[c+1] : 0.f;
    float acc = fcb[c] + w1d[0]*zm1 + w1d[1]*za[c] + w1d[2]*zp1;
    const float* wr = fcw + (size_t)c * CC;
    for(int k = 0; k < CC; k++) acc += za[k] * wr[k];
    gate[b * CC + c] = sigmf(acc);
}

// ------ K4a (tier3): LN + full in_proj (x AND z halves) per 128-pos tile ---------
// Per-lane coalesced staging (16 lines in flight per instruction) + weights in
// VGPRs + LDS-broadcast x rows. Proven 234 us; the LDS-free wave-uniform variant
// (round 5) regressed to 358 us — broadcast loads give 1 line/instr -> low MLP.
__global__ __launch_bounds__(256) void k_inproj(const float* __restrict__ x,
        const float* __restrict__ mrs, const float* __restrict__ nw,
        const float* __restrict__ nb, const float* __restrict__ ipw,
        const float* __restrict__ ipb, float* __restrict__ xib,
        float* __restrict__ zbuf){
    int tile = blockIdx.x, b = blockIdx.y, g = blockIdx.z;
    int n0 = tile * 128;
    __shared__ float xs[128 * 64];
    int tid = threadIdx.x;
    for(int idx = tid; idx < 2048; idx += 256){
        int p = idx >> 4, k4 = (idx & 15) * 4;
        size_t r = (size_t)b * NN + n0 + p;
        float4 v = *(const float4*)(x + r * CC + g*64 + k4);
        float m = mrs[2*r], rs = mrs[2*r+1];
        float4 w4 = *(const float4*)(nw + g*64 + k4);
        float4 b4 = *(const float4*)(nb + g*64 + k4);
        float4 o;
        o.x = (v.x - m)*rs*w4.x + b4.x;
        o.y = (v.y - m)*rs*w4.y + b4.y;
        o.z = (v.z - m)*rs*w4.z + b4.z;
        o.w = (v.w - m)*rs*w4.w + b4.w;
        *(float4*)(xs + p*64 + k4) = o;
    }
    __syncthreads();
    int c = tid & 63, ph = tid >> 6;   // channel c (both halves), position quarter
    float wx[64], wz[64];
    {
        const float* wrx = ipw + ((size_t)(g*128 + c)) * 64;
        const float* wrz = ipw + ((size_t)(g*128 + 64 + c)) * 64;
        #pragma unroll
        for(int k = 0; k < 64; k++){ wx[k] = wrx[k]; wz[k] = wrz[k]; }
    }
    float bx = ipb[g*128 + c], bz = ipb[g*128 + 64 + c];
    size_t obase = ((size_t)(b*4 + g)) * NN + n0;
    for(int p = ph*32; p < ph*32 + 32; p++){
        const float4* xp = (const float4*)(xs + p*64);
        float a0 = 0.f, a1 = 0.f, z0 = 0.f, z1 = 0.f;
        #pragma unroll
        for(int k4 = 0; k4 < 16; k4 += 2){
            float4 u = xp[k4], v = xp[k4+1];
            a0 += u.x*wx[4*k4+0]; a1 += u.y*wx[4*k4+1];
            a0 += u.z*wx[4*k4+2]; a1 += u.w*wx[4*k4+3];
            z0 += u.x*wz[4*k4+0]; z1 += u.y*wz[4*k4+1];
            z0 += u.z*wz[4*k4+2]; z1 += u.w*wz[4*k4+3];
            a0 += v.x*wx[4*k4+4]; a1 += v.y*wx[4*k4+5];
            a0 += v.z*wx[4*k4+6]; a1 += v.w*wx[4*k4+7];
            z0 += v.x*wz[4*k4+4]; z1 += v.y*wz[4*k4+5];
            z0 += v.z*wz[4*k4+6]; z1 += v.w*wz[4*k4+7];
        }
        float xv = bx + a0 + a1;
        float zv = bz + z0 + z1;
        xib[(obase + p)*64 + c] = xv;
        zbuf[(obase + p)*64 + c] = zv * sigmf(zv);
    }
}

// ------ K4b (tier3): depthwise conv3x3 + silu, halo from global xi ---------------
__global__ __launch_bounds__(256) void k_conv(const float* __restrict__ xib,
        const float* __restrict__ cw, const float* __restrict__ cb,
        float* __restrict__ out){
    int tile = blockIdx.x, b = blockIdx.y, g = blockIdx.z;
    int h0 = (tile/12)*8, w0 = (tile%12)*8;
    __shared__ float xs[100*64];
    int tid = threadIdx.x;
    size_t ibase = ((size_t)(b*4+g)) * NN;
    for(int i = tid; i < 6400; i += 256){
        int p = i >> 6, k = i & 63;
        int ph = h0 + p/10 - 1, pw = w0 + p%10 - 1;
        float v = 0.f;
        if(ph >= 0 && ph < HH && pw >= 0 && pw < WWI)
            v = xib[(ibase + (size_t)(ph*WWI + pw))*64 + k];
        xs[i] = v;
    }
    __syncthreads();
    int c = tid & 63, q = tid >> 6;
    float wk[9];
    const float* wp = cw + ((size_t)(g*64 + c))*9;
    #pragma unroll
    for(int j = 0; j < 9; j++) wk[j] = wp[j];
    float bias2 = cb[g*64 + c];
    for(int pi = q*16; pi < q*16+16; pi++){
        int py = pi >> 3, px = pi & 7;
        float acc = bias2;
        #pragma unroll
        for(int dy = 0; dy < 3; dy++)
            #pragma unroll
            for(int dx = 0; dx < 3; dx++)
                acc += xs[((py+dy)*10 + px+dx)*64 + c] * wk[dy*3+dx];
        float sv = acc * sigmf(acc);
        size_t r = (size_t)b*NN + (h0+py)*WWI + (w0+px);
        out[r*CC + g*64 + c] = sv;
    }
}

// ------ K4 (fallback): fused LN + in_proj(x half) + depthwise conv3x3 + silu -----
template<int ZPRE>
__global__ __launch_bounds__(256) void k_ipconv(const float* __restrict__ x,
        const float* __restrict__ mrs, const float* __restrict__ nw,
        const float* __restrict__ nb, const float* __restrict__ ipw,
        const float* __restrict__ ipb, const float* __restrict__ cw,
        const float* __restrict__ cb, float* __restrict__ out,
        float* __restrict__ zbuf){
    int tile = blockIdx.x, b = blockIdx.y, g = blockIdx.z;
    int h0 = (tile / 12) * 8, w0 = (tile % 12) * 8;
    __shared__ float xs[100 * 64];
    __shared__ float xi[100 * 64];
    int tid = threadIdx.x;
    for(int i = tid; i < 6400; i += 256){
        int p = i >> 6, k = i & 63;
        int ph = h0 + p / 10 - 1, pw = w0 + p % 10 - 1;
        float v = 0.f;
        if(ph >= 0 && ph < HH && pw >= 0 && pw < WWI){
            size_t r = (size_t)b * NN + ph * WWI + pw;
            v = (x[r * CC + g*64 + k] - mrs[2*r]) * mrs[2*r+1]
                * nw[g*64 + k] + nb[g*64 + k];
        }
        xs[i] = v;
    }
    __syncthreads();
    int c = tid & 63, q = tid >> 6;
    {
        float wv[64];
        const float* wr = ipw + ((size_t)(g * 128 + c)) * 64;
        #pragma unroll
        for(int k = 0; k < 64; k++) wv[k] = wr[k];
        float bias = ipb[g * 128 + c];
        for(int p = q * 25; p < q * 25 + 25; p++){
            int ph = h0 + p / 10 - 1, pw = w0 + p % 10 - 1;
            bool valid = (ph >= 0 && ph < HH && pw >= 0 && pw < WWI);
            float acc = bias;
            const float* xp = &xs[p * 64];
            #pragma unroll
            for(int k = 0; k < 64; k++) acc += xp[k] * wv[k];
            xi[p * 64 + c] = valid ? acc : 0.f;   // conv zero-pads AFTER in_proj
        }
    }
    __syncthreads();
    float wk[9];
    const float* wp = cw + ((size_t)(g * 64 + c)) * 9;
    #pragma unroll
    for(int j = 0; j < 9; j++) wk[j] = wp[j];
    float bias2 = cb[g * 64 + c];
    for(int pi = q * 16; pi < q * 16 + 16; pi++){
        int py = pi >> 3, px = pi & 7;
        float acc = bias2;
        #pragma unroll
        for(int dy = 0; dy < 3; dy++)
            #pragma unroll
            for(int dx = 0; dx < 3; dx++)
                acc += xi[((py + dy) * 10 + px + dx) * 64 + c] * wk[dy*3 + dx];
        float sv = acc * sigmf(acc);
        size_t r = (size_t)b * NN + (h0 + py) * WWI + (w0 + px);
        out[r * CC + g*64 + c] = sv;
    }
    if(ZPRE){
        float wzv[64];
        const float* wr = ipw + ((size_t)(g * 128 + 64 + c)) * 64;
        #pragma unroll
        for(int k = 0; k < 64; k++) wzv[k] = wr[k];
        float zbv = ipb[g * 128 + 64 + c];
        size_t zb0 = ((size_t)(b * 4 + g)) * NN;
        for(int p16 = 0; p16 < 16; p16++){
            int p = q * 16 + p16;
            int py = p >> 3, px = p & 7;
            const float* xp = &xs[((py + 1) * 10 + (px + 1)) * 64];
            float acc = zbv;
            #pragma unroll
            for(int k = 0; k < 64; k++) acc += xp[k] * wzv[k];
            zbuf[(zb0 + (size_t)((h0 + py) * WWI + (w0 + px))) * 64 + c]
                = acc * sigmf(acc);
        }
    }
}

// ---------------- K5: scan phase 1 — on-the-fly xdbl, prod(a), h_end -------------
__global__ __launch_bounds__(64) void k_scan1(const float* __restrict__ out,
        const float* __restrict__ xpw, const float* __restrict__ dtw,
        const float* __restrict__ dtb, const float* __restrict__ alog,
        float* __restrict__ ap_out, float* __restrict__ h_out){
    int chunk = blockIdx.x, gb = blockIdx.y;
    int g = gb >> 3, b = gb & 7, d = threadIdx.x;
    __shared__ float s_seq[CHK * 65];
    __shared__ float s_xd[CHK * 6];
    __shared__ float s_w[6 * 64];
    int base, step; chunk_walk(g, chunk, base, step);
    const float* xg = out + (size_t)b * NN * CC + g * 64;
    for(int j = 0; j < CHK; j++)
        s_seq[j * 65 + d] = xg[(size_t)(base + j * step) * CC + d];
    for(int i = d; i < 384; i += 64) s_w[i] = xpw[g * 384 + i];
    __syncthreads();
    for(int idx = d; idx < CHK*6; idx += 64){
        int l = idx / 6, j = idx % 6;
        float acc = 0.f;
        const float* sr = &s_seq[l * 65];
        const float* wr = &s_w[j * 64];
        #pragma unroll
        for(int k = 0; k < 64; k++) acc += sr[k] * wr[k];
        s_xd[idx] = acc;
    }
    __syncthreads();
    int gd = g * 64 + d;
    float Av = -expf(alog[gd]);
    float db = dtb[gd];
    float w0 = dtw[gd*4], w1 = dtw[gd*4+1], w2 = dtw[gd*4+2], w3 = dtw[gd*4+3];
    float h = 0.f, apd = 1.f;
    #pragma unroll 4
    for(int l = 0; l < CHK; l++){
        const float* xd = &s_xd[l * 6];
        float xv = s_seq[l*65 + d];
        float dt = softplusf(xd[0]*w0 + xd[1]*w1 + xd[2]*w2 + xd[3]*w3 + db);
        float a = expf(dt * Av);
        h = a*h + dt*xv*xd[4];
        apd *= a;
    }
    int ob = (gb * NCH + chunk) * 64 + d;
    ap_out[ob] = apd; h_out[ob] = h;
}

// ---------------- K6: scan phase 2 — serial scan over chunk summaries ------------
__global__ __launch_bounds__(256) void k_scan2(const float* __restrict__ ap,
        const float* __restrict__ he, float* __restrict__ hinit){
    int idx = blockIdx.x * 256 + threadIdx.x;   // 0..2047
    int gb = idx >> 6, d = idx & 63;
    float h = 0.f;
    for(int c = 0; c < NCH; c++){
        int o = (gb * NCH + c) * 64 + d;
        hinit[o] = h;
        h = ap[o]*h + he[o];
    }
}

// --- K7: scan phase 3 + out_norm LN + silu(z) gate, IN PLACE ---------------------
template<int ZPRE>
__global__ __launch_bounds__(64) void k_scan3(float* __restrict__ out,
        const float* __restrict__ x, const float* __restrict__ mrs,
        const float* __restrict__ nw, const float* __restrict__ nb,
        const float* __restrict__ ipw, const float* __restrict__ ipb,
        const float* __restrict__ xpw, const float* __restrict__ dtw,
        const float* __restrict__ dtb, const float* __restrict__ alog,
        const float* __restrict__ Dsp, const float* __restrict__ onw,
        const float* __restrict__ onb, const float* __restrict__ hinit,
        const float* __restrict__ zbuf){
    int chunk = blockIdx.x, gb = blockIdx.y;
    int g = gb >> 3, b = gb & 7, d = threadIdx.x;
    __shared__ float s_seq[CHK * 65];          // seq, then y (overwritten in place)
    __shared__ float s_xd[CHK * 6];
    __shared__ float s_w[6 * 64];
    __shared__ float xnt[(ZPRE ? 1 : CHK) * 65];
    int base, step; chunk_walk(g, chunk, base, step);
    float* xg = out + (size_t)b * NN * CC + g * 64;
    for(int j = 0; j < CHK; j++)
        s_seq[j * 65 + d] = xg[(size_t)(base + j * step) * CC + d];
    if(!ZPRE){
        float nwv = nw[g*64 + d], nbv = nb[g*64 + d];
        for(int j = 0; j < CHK; j++){
            int n = base + j * step;
            size_t r = (size_t)b * NN + n;
            xnt[j * 65 + d] = (x[r * CC + g*64 + d] - mrs[2*r]) * mrs[2*r+1] * nwv + nbv;
        }
    }
    for(int i = d; i < 384; i += 64) s_w[i] = xpw[g * 384 + i];
    __syncthreads();
    for(int idx = d; idx < CHK*6; idx += 64){
        int l = idx / 6, j = idx % 6;
        float acc = 0.f;
        const float* sr = &s_seq[l * 65];
        const float* wr = &s_w[j * 64];
        #pragma unroll
        for(int k = 0; k < 64; k++) acc += sr[k] * wr[k];
        s_xd[idx] = acc;
    }
    __syncthreads();
    int gd = g * 64 + d;
    float Av = -expf(alog[gd]);
    float db = dtb[gd];
    float Dv = Dsp[gd];
    float w0 = dtw[gd*4], w1 = dtw[gd*4+1], w2 = dtw[gd*4+2], w3 = dtw[gd*4+3];
    float h = hinit[(gb * NCH + chunk) * 64 + d];
    // ---- Phase A: scan. Only h is loop-carried; y overwrites s_seq row. ----
    #pragma unroll 4
    for(int l = 0; l < CHK; l++){
        const float* xd = &s_xd[l * 6];
        float xv = s_seq[l*65 + d];
        float dt = softplusf(xd[0]*w0 + xd[1]*w1 + xd[2]*w2 + xd[3]*w3 + db);
        float a = expf(dt * Av);
        h = a*h + dt*xv*xd[4];
        s_seq[l*65 + d] = h * xd[5] + Dv * xv;
    }
    // ---- Phase B: out_norm LN + silu(z) gate. Iterations independent. ----
    float wON = onw[gd], bON = onb[gd];
    float wz[ZPRE ? 1 : 64];
    float zb = 0.f;
    if(!ZPRE){
        const float* wr = ipw + ((size_t)(g * 128 + 64 + d)) * 64;
        #pragma unroll
        for(int k = 0; k < 64; k++) wz[k] = wr[k];
        zb = ipb[g * 128 + 64 + d];
    }
    const float* zp = zbuf + (((size_t)(b * 4 + g)) * NN) * 64 + d;
    #pragma unroll 4
    for(int l = 0; l < CHK; l++){
        float y = s_seq[l*65 + d];
        float s = y, q = y * y;
        wredsum2(s, q);
        float m = s * (1.f/64.f);
        float var = q * (1.f/64.f) - m*m;
        float rs = rsqrtf(fmaxf(var, 0.f) + 1e-5f);
        float lny = (y - m) * rs * wON + bON;
        int n = base + l * step;
        float zs;
        if(ZPRE){
            zs = zp[(size_t)n * 64];
        } else {
            float z = zb;
            const float* xp = &xnt[l * 65];
            #pragma unroll
            for(int k = 0; k < 64; k++) z += xp[k] * wz[k];
            zs = z * sigmf(z);
        }
        xg[(size_t)n * CC + d] = lny * zs;   // in-place (own tile)
    }
}

// --- K8 (fallback): out_proj + skip*xn*gate, spatial tiles, IN PLACE -------------
__global__ __launch_bounds__(64) void k_out2(float* __restrict__ out,
        const float* __restrict__ x, const float* __restrict__ mrs,
        const float* __restrict__ nw, const float* __restrict__ nb,
        const float* __restrict__ opw, const float* __restrict__ opb,
        const float* __restrict__ gate, const float* __restrict__ skip){
    int tile = blockIdx.x, b = blockIdx.y, g = blockIdx.z;
    int n0 = tile * 64, t = threadIdx.x;
    __shared__ float ly[64 * 65];
    __shared__ float xnt[64 * 65];
    float* xg = out + (size_t)b * NN * CC + g * 64;
    float nwv = nw[g*64 + t], nbv = nb[g*64 + t];
    for(int p = 0; p < 64; p++){
        size_t r = (size_t)b * NN + n0 + p;
        ly[p * 65 + t] = xg[(size_t)(n0 + p) * CC + t];
        xnt[p * 65 + t] = (x[r * CC + g*64 + t] - mrs[2*r]) * mrs[2*r+1] * nwv + nbv;
    }
    __syncthreads();
    float wv[64];
    const float* wr = opw + ((size_t)(g * 64 + t)) * 64;
    #pragma unroll
    for(int k = 0; k < 64; k++) wv[k] = wr[k];
    float bias = opb[g * 64 + t];
    float gv = gate[b * CC + g*64 + t];
    float sk = skip[0];
    for(int p = 0; p < 64; p++){
        float acc = bias;
        const float* yp = &ly[p * 65];
        #pragma unroll
        for(int k = 0; k < 64; k++) acc += yp[k] * wv[k];
        xg[(size_t)(n0 + p) * CC + t] = acc * sk * xnt[p * 65 + t] * gv;
    }
}

// --- K8new: out_proj + skip*xn*gate + fused row-stats, LDS-free ------------------
__global__ __launch_bounds__(256) void k_out3(const float* __restrict__ yin,
        const float* __restrict__ x, const float* __restrict__ mrs,
        const float* __restrict__ nw, const float* __restrict__ nb,
        const float* __restrict__ opw, const float* __restrict__ opb,
        const float* __restrict__ gate, const float* __restrict__ skip,
        float* __restrict__ zo, float* __restrict__ mrs2){
    __shared__ float ps[16 * 4], pq[16 * 4];
    int o = threadIdx.x;
    int g = o >> 6, c = o & 63;
    int r0 = blockIdx.x * 16;           // 16 rows/block; NN%16==0 -> same b
    int b  = r0 / NN;
    int n0 = r0 - b * NN;
    float wv[64];
    {
        const float4* wr = (const float4*)(opw + ((size_t)(g*64 + c)) * 64);
        #pragma unroll
        for(int j = 0; j < 16; j++){
            float4 t4 = wr[j];
            wv[4*j+0] = t4.x; wv[4*j+1] = t4.y;
            wv[4*j+2] = t4.z; wv[4*j+3] = t4.w;
        }
    }
    float acc[16];
    const float* ab = yin + ((size_t)b * NN + n0) * CC + g * 64;
    #pragma unroll 4
    for(int r = 0; r < 16; r++){
        const float4* ar = (const float4*)(ab + (size_t)r * CC);  // wave-uniform
        float s0 = 0.f, s1 = 0.f;
        #pragma unroll
        for(int j = 0; j < 8; j++){
            float4 u = ar[j], v = ar[j + 8];
            s0 += u.x*wv[4*j+0]  + u.y*wv[4*j+1]  + u.z*wv[4*j+2]  + u.w*wv[4*j+3];
            s1 += v.x*wv[32+4*j] + v.y*wv[33+4*j] + v.z*wv[34+4*j] + v.w*wv[35+4*j];
        }
        acc[r] = s0 + s1;
    }
    float bias = opb[g*64 + c];
    float gv = gate[b * CC + g*64 + c];
    float sk = skip[0];
    float nwv = nw[g*64 + c], nbv = nb[g*64 + c];
    size_t zbase = ((size_t)(b*4 + g)) * NN + n0;
    #pragma unroll
    for(int r = 0; r < 16; r++){
        size_t row = (size_t)r0 + r;
        float xv = x[row * CC + g*64 + c];           // per-lane coalesced
        float xn = (xv - mrs[2*row]) * mrs[2*row+1] * nwv + nbv;
        float res = (acc[r] + bias) * sk * xn * gv;
        acc[r] = res;
        zo[(zbase + r) * 64 + c] = res;
    }
    // fused row stats over 256 channels (64 lanes x 4 waves)
    #pragma unroll
    for(int r = 0; r < 16; r++){
        float s = acc[r], q = acc[r] * acc[r];
        wredsum2(s, q);
        if(c == 0){ ps[r*4 + g] = s; pq[r*4 + g] = q; }
    }
    __syncthreads();
    if(o < 16){
        float ss = ps[o*4] + ps[o*4+1] + ps[o*4+2] + ps[o*4+3];
        float qq = pq[o*4] + pq[o*4+1] + pq[o*4+2] + pq[o*4+3];
        float m = ss * (1.f/256.f);
        float var = qq * (1.f/256.f) - m*m;
        mrs2[2*((size_t)r0 + o)]     = m;
        mrs2[2*((size_t)r0 + o) + 1] = rsqrtf(fmaxf(var, 0.f) + 1e-5f);
    }
}

// ---------------- K9 (fallback): final LN + proj GEMM, IN PLACE ------------------
__global__ __launch_bounds__(256) void k_final(float* __restrict__ out,
        const float* __restrict__ nw, const float* __restrict__ nb,
        const float* __restrict__ pw, const float* __restrict__ pb){
    __shared__ float A[16 * 256];
    __shared__ float ps[256], pq[256];
    __shared__ float mrow[16], rrow[16];
    int n0 = blockIdx.x * 16;
    for(int i = threadIdx.x; i < 4096; i += 256)
        A[i] = out[(size_t)n0 * CC + i];
    __syncthreads();
    {
        int r = threadIdx.x >> 4, t16 = threadIdx.x & 15;
        float s = 0.f, q = 0.f;
        for(int j = 0; j < 16; j++){
            float v = A[r*256 + t16*16 + j];
            s += v; q += v*v;
        }
        ps[threadIdx.x] = s; pq[threadIdx.x] = q;
    }
    __syncthreads();
    if(threadIdx.x < 16){
        float ss = 0.f, qq = 0.f;
        for(int j = 0; j < 16; j++){ ss += ps[threadIdx.x*16 + j]; qq += pq[threadIdx.x*16 + j]; }
        float m = ss * (1.f/256.f);
        float var = qq * (1.f/256.f) - m*m;
        mrow[threadIdx.x] = m;
        rrow[threadIdx.x] = rsqrtf(fmaxf(var, 0.f) + 1e-5f);
    }
    __syncthreads();
    for(int i = threadIdx.x; i < 4096; i += 256){
        int r = i >> 8, c = i & 255;
        A[i] = (A[i] - mrow[r]) * rrow[r] * nw[c] + nb[c];
    }
    __syncthreads();
    int o = threadIdx.x;
    float acc[16];
    #pragma unroll
    for(int p = 0; p < 16; p++) acc[p] = 0.f;
    for(int kt = 0; kt < 4; kt++){
        float wv[64];
        const float4* wr = (const float4*)(pw + (size_t)o * CC + kt * 64);
        #pragma unroll
        for(int j = 0; j < 16; j++){
            float4 tq = wr[j];
            wv[4*j+0] = tq.x; wv[4*j+1] = tq.y;
            wv[4*j+2] = tq.z; wv[4*j+3] = tq.w;
        }
        #pragma unroll
        for(int p = 0; p < 16; p++){
            const float* ar = &A[p*256 + kt*64];
            float a = 0.f;
            #pragma unroll
            for(int k = 0; k < 64; k++) a += ar[k] * wv[k];
            acc[p] += a;
        }
    }
    float pbv = pb[o];
    #pragma unroll
    for(int p = 0; p < 16; p++)
        out[(size_t)(n0 + p) * CC + o] = acc[p] + pbv;
}

// ---------------- K9new: LN-folded proj GEMM, LDS-free ---------------------------
__global__ __launch_bounds__(256) void k_final2(const float* __restrict__ y,
        const float* __restrict__ mrs2, const float* __restrict__ Wn,
        const float* __restrict__ wsum, const float* __restrict__ cvec,
        float* __restrict__ out){
    int o = threadIdx.x;
    int r0 = blockIdx.x * 16;           // global row base (16 rows/block)
    int b  = r0 / NN;
    int n0 = r0 - b * NN;               // NN divisible by 16: all rows same b
    float acc[16];
    #pragma unroll
    for(int r = 0; r < 16; r++) acc[r] = 0.f;
    for(int kt = 0; kt < 4; kt++){
        float wv[64];
        const float4* wr = (const float4*)(Wn + (size_t)o * 256 + kt * 64);
        #pragma unroll
        for(int j = 0; j < 16; j++){
            float4 t4 = wr[j];
            wv[4*j+0] = t4.x; wv[4*j+1] = t4.y;
            wv[4*j+2] = t4.z; wv[4*j+3] = t4.w;
        }
        const float* ab = y + ((size_t)(b*4 + kt)*NN + n0) * 64;
        #pragma unroll 4
        for(int r = 0; r < 16; r++){
            const float* ar = ab + (size_t)r * 64;   // wave-uniform address
            float s0 = 0.f, s1 = 0.f;
            #pragma unroll
            for(int j = 0; j < 32; j++){
                s0 += ar[j]      * wv[j];
                s1 += ar[j + 32] * wv[j + 32];
            }
            acc[r] += s0 + s1;
        }
    }
    float wso = wsum[o], co = cvec[o];
    #pragma unroll
    for(int r = 0; r < 16; r++){
        float m  = mrs2[2*(size_t)(r0 + r)];
        float rs = mrs2[2*(size_t)(r0 + r) + 1];
        out[(size_t)(r0 + r) * CC + o] = rs * acc[r] - m * rs * wso + co;
    }
}

extern "C" void kernel_launch(void* const* d_in, const int* in_sizes, int n_in,
                              void* d_out, int out_size, void* d_ws, size_t ws_size,
                              hipStream_t stream){
    const float* x    = (const float*)d_in[0];
    const float* nw   = (const float*)d_in[1];
    const float* nb   = (const float*)d_in[2];
    const float* fcw  = (const float*)d_in[3];
    const float* fcb  = (const float*)d_in[4];
    const float* w1d  = (const float*)d_in[5];
    const float* ipw  = (const float*)d_in[6];
    const float* ipb  = (const float*)d_in[7];
    const float* cw   = (const float*)d_in[8];
    const float* cb   = (const float*)d_in[9];
    const float* xpw  = (const float*)d_in[10];
    const float* dtw  = (const float*)d_in[11];
    const float* dtb  = (const float*)d_in[12];
    const float* alog = (const float*)d_in[13];
    const float* Dsp  = (const float*)d_in[14];
    const float* onw  = (const float*)d_in[15];
    const float* onb  = (const float*)d_in[16];
    const float* opw  = (const float*)d_in[17];
    const float* opb  = (const float*)d_in[18];
    const float* pw   = (const float*)d_in[19];
    const float* pb   = (const float*)d_in[20];
    const float* skip = (const float*)d_in[21];

    // Workspace layout:
    //   base 2,957,312 | zbuf 75,497,472 | mrs2 589,824 | Wn 262,144
    //   | wsum 1,024 | cvec 1,024   -> T2 = 79,308,800
    //   | xib 75,497,472            -> T3 = 154,806,272
    char* base = (char*)d_ws;
    float* mrs  = (float*)base;                      //   589,824 B
    float* gate = (float*)(base +  589824ull);       //     8,192 B
    float* ap   = (float*)(base +  598016ull);       //   786,432 B (zpart aliases)
    float* he   = (float*)(base + 1384448ull);       //   786,432 B
    float* hi   = (float*)(base + 2170880ull);       //   786,432 B
    float* zbuf = (float*)(base + 2957312ull);       //  75,497,472 B
    float* mrs2 = (float*)(base + 78454784ull);      //   589,824 B
    float* Wn   = (float*)(base + 79044608ull);      //   262,144 B
    float* wsum = (float*)(base + 79306752ull);      //     1,024 B
    float* cvec = (float*)(base + 79307776ull);      //     1,024 B
    float* xib  = (float*)(base + 79308800ull);      //  75,497,472 B
    float* zpart = ap;                               // dead before k_scan1 writes ap
    float* out  = (float*)d_out;                     // spatial (B,N,256) scratch
    (void)in_sizes; (void)n_in; (void)out_size;

    const size_t T1 = 78454784ull;    // base + zbuf
    const size_t T2 = 79308800ull;    // + mrs2 + Wn + wsum + cvec
    const size_t T3 = 154806272ull;   // + xib
    bool usez    = ws_size >= T1;
    bool usef2   = ws_size >= T2;
    bool usesplit= ws_size >= T3;

    if(usef2)
        k_prew<<<1, 256, 0, stream>>>(pw, nw, nb, pb, Wn, wsum, cvec);
    k_stats <<<18432, 256, 0, stream>>>(x, mrs);
    k_zavg  <<<dim3(36, 8), 256, 0, stream>>>(x, mrs, nw, nb, zpart);
    k_gate  <<<8, 256, 0, stream>>>(zpart, fcw, fcb, w1d, gate);
    if(usesplit){
        k_inproj<<<dim3(72, 8, 4), 256, 0, stream>>>(x, mrs, nw, nb, ipw, ipb,
                                                     xib, zbuf);
        k_conv  <<<dim3(144, 8, 4), 256, 0, stream>>>(xib, cw, cb, out);
    } else if(usez){
        k_ipconv<1><<<dim3(144, 8, 4), 256, 0, stream>>>(x, mrs, nw, nb, ipw, ipb,
                                                         cw, cb, out, zbuf);
    } else {
        k_ipconv<0><<<dim3(144, 8, 4), 256, 0, stream>>>(x, mrs, nw, nb, ipw, ipb,
                                                         cw, cb, out, zbuf);
    }
    k_scan1 <<<dim3(96, 32), 64, 0, stream>>>(out, xpw, dtw, dtb, alog, ap, he);
    k_scan2 <<<8, 256, 0, stream>>>(ap, he, hi);
    if(usez){
        k_scan3<1><<<dim3(96, 32), 64, 0, stream>>>(out, x, mrs, nw, nb, ipw, ipb,
                                                    xpw, dtw, dtb, alog, Dsp, onw,
                                                    onb, hi, zbuf);
    } else {
        k_scan3<0><<<dim3(96, 32), 64, 0, stream>>>(out, x, mrs, nw, nb, ipw, ipb,
                                                    xpw, dtw, dtb, alog, Dsp, onw,
                                                    onb, hi, zbuf);
    }
    if(usef2){
        k_out3  <<<4608, 256, 0, stream>>>(out, x, mrs, nw, nb, opw, opb,
                                           gate, skip, zbuf, mrs2);
        k_final2<<<4608, 256, 0, stream>>>(zbuf, mrs2, Wn, wsum, cvec, out);
    } else {
        k_out2  <<<dim3(144, 8, 4), 64, 0, stream>>>(out, x, mrs, nw, nb, opw, opb,
                                                     gate, skip);
        k_final <<<4608, 256, 0, stream>>>(out, nw, nb, pw, pb);
    }
}

// Round 8
// 1118.278 us; speedup vs baseline: 1.2051x; 1.0979x over previous
//
#include <hip/hip_runtime.h>
#include <math.h>
#include <stdint.h>

#define HH 96
#define WWI 96
#define NN 9216        // H*W
#define CC 256
#define LL 9216
#define CHK 96
#define NCH 96
#define BB 8
#define BN (BB*NN)     // 73728

typedef float f32x16 __attribute__((ext_vector_type(16)));
typedef float f32x2  __attribute__((ext_vector_type(2)));

__device__ __forceinline__ float softplusf(float x){
    float e = expf(-fabsf(x));
    return fmaxf(x, 0.f) + log1pf(e);
}
__device__ __forceinline__ float sigmf(float x){ return 1.f / (1.f + expf(-x)); }

__device__ __forceinline__ float wredsum(float v){
    #pragma unroll
    for(int o = 32; o > 0; o >>= 1) v += __shfl_xor(v, o, 64);
    return v;
}

// paired reduction: s and q interleaved so the two shfl chains overlap
__device__ __forceinline__ void wredsum2(float& s, float& q){
    #pragma unroll
    for(int o = 32; o > 0; o >>= 1){
        s += __shfl_xor(s, o, 64);
        q += __shfl_xor(q, o, 64);
    }
}

// wave-uniform pointer -> SGPR-class 64-bit address (readfirstlane hoist)
__device__ __forceinline__ unsigned long long rfl64(const void* p){
    unsigned long long a = (unsigned long long)(uintptr_t)p;
    unsigned int lo = __builtin_amdgcn_readfirstlane((unsigned int)a);
    unsigned int hi = __builtin_amdgcn_readfirstlane((unsigned int)(a >> 32));
    return ((unsigned long long)hi << 32) | lo;
}

// scan chunk -> spatial walk: n = base + j*step, j = 0..95 (within-chunk scan order)
__device__ __forceinline__ void chunk_walk(int g, int chunk, int& base, int& step){
    if(g == 0){ base = chunk * 96;        step = 1;   }
    else if(g == 1){ base = 9215 - chunk * 96; step = -1; }
    else if(g == 2){ base = chunk;        step = 96;  }
    else { base = 9215 - chunk;           step = -96; }
}

// ---------------- K1: per-row LN stats of x -> mrs (mean, rstd) ------------------
__global__ __launch_bounds__(256) void k_stats(const float* __restrict__ x,
                                               float* __restrict__ mrs){
    int wid = threadIdx.x >> 6, lane = threadIdx.x & 63;
    size_t row = (size_t)blockIdx.x * 4 + wid;
    float4 v = ((const float4*)(x + row * CC))[lane];
    float s = wredsum(v.x + v.y + v.z + v.w);
    float q = wredsum(v.x*v.x + v.y*v.y + v.z*v.z + v.w*v.w);
    float m = s * (1.f/256.f);
    float var = q * (1.f/256.f) - m*m;
    float rs = rsqrtf(fmaxf(var, 0.f) + 1e-5f);
    if(lane == 0){ mrs[2*row] = m; mrs[2*row+1] = rs; }
}

// ------------- K1c: fold final LN into proj weights --------------------------------
__global__ __launch_bounds__(256) void k_prew(const float* __restrict__ pw,
        const float* __restrict__ nw, const float* __restrict__ nb,
        const float* __restrict__ pb, float* __restrict__ Wn,
        float* __restrict__ wsum, float* __restrict__ cvec){
    int o = threadIdx.x;
    float ws = 0.f, cc = 0.f;
    for(int k = 0; k < 256; k++){
        float w = pw[(size_t)o * 256 + k];
        float wn = w * nw[k];
        Wn[(size_t)o * 256 + k] = wn;
        ws += wn; cc += w * nb[k];
    }
    wsum[o] = ws; cvec[o] = cc + pb[o];
}

// ------------- K1d: fold x-LN into in_proj weights -------------------------------
// Wip[(g*128+o)*64+k] = ipw[g,o,k]*nw[g*64+k]
// wsip = sum_k Wip;  cvip = sum_k ipw*nb + ipb    (verified correct in round 6)
__global__ __launch_bounds__(128) void k_prewip(const float* __restrict__ ipw,
        const float* __restrict__ nw, const float* __restrict__ nb,
        const float* __restrict__ ipb, float* __restrict__ Wip,
        float* __restrict__ wsip, float* __restrict__ cvip){
    int g = blockIdx.x, o = threadIdx.x;
    const float* wr = ipw + ((size_t)(g*128 + o)) * 64;
    float ws = 0.f, cc = 0.f;
    for(int k = 0; k < 64; k++){
        float w = wr[k];
        float wn = w * nw[g*64 + k];
        Wip[((size_t)(g*128 + o))*64 + k] = wn;
        ws += wn; cc += w * nb[g*64 + k];
    }
    wsip[g*128 + o] = ws;
    cvip[g*128 + o] = cc + ipb[g*128 + o];
}

// ---------------- K2: partial column sums of LN(x) -> zpart ----------------------
__global__ __launch_bounds__(256) void k_zavg(const float* __restrict__ x,
        const float* __restrict__ mrs, const float* __restrict__ nw,
        const float* __restrict__ nb, float* __restrict__ zpart){
    int c = threadIdx.x, b = blockIdx.y, t0 = blockIdx.x * 256;
    float nwv = nw[c], nbv = nb[c];
    float s = 0.f;
    for(int i = 0; i < 256; i++){
        size_t r = (size_t)b * NN + t0 + i;
        s += (x[r * CC + c] - mrs[2*r]) * mrs[2*r+1] * nwv + nbv;
    }
    zpart[((size_t)b * 36 + blockIdx.x) * CC + c] = s;
}

// ---------------- K3: gate = sigmoid(z@fc_w.T + fc_b + conv1d(z)) ----------------
__global__ __launch_bounds__(256) void k_gate(const float* __restrict__ zpart,
        const float* __restrict__ fcw, const float* __restrict__ fcb,
        const float* __restrict__ w1d, float* __restrict__ gate){
    __shared__ float za[CC];
    int c = threadIdx.x, b = blockIdx.x;
    float s = 0.f;
    for(int t = 0; t < 36; t++) s += zpart[((size_t)b * 36 + t) * CC + c];
    za[c] = s * (1.f/(float)NN);
    __syncthreads();
    float zm1 = (c > 0)     ? za[c-1] : 0.f;
    float zp1 = (c < CC-1)  ? za[c+1] : 0.f;
    float acc = fcb[c] + w1d[0]*zm1 + w1d[1]*za[c] + w1d[2]*zp1;
    const float* wr = fcw + (size_t)c * CC;
    for(int k = 0; k < CC; k++) acc += za[k] * wr[k];
    gate[b * CC + c] = sigmf(acc);
}

// ------ K4a3 (tier4): LN-folded in_proj, SCALAR-broadcast x, zero LDS ------------
// Wave-uniform x-row loaded via s_load_dwordx16 into SGPRs (scalar cache path:
// no LDS pipe, no VALU cost, v_fmac v,s,v). Weights per-lane in VGPRs. No
// barriers; FMA-bound. LN folded into Wip/wsip/cvip (round-6-verified formula).
__global__ __launch_bounds__(256) void k_inproj3(const float* __restrict__ x,
        const float* __restrict__ mrs, const float* __restrict__ Wip,
        const float* __restrict__ wsip, const float* __restrict__ cvip,
        float* __restrict__ xib, float* __restrict__ zbuf){
    int tile = blockIdx.x, b = blockIdx.y, g = blockIdx.z;
    int n0 = tile * 128;
    int c = threadIdx.x & 63, q = threadIdx.x >> 6;
    float wx[64], wz[64];
    {
        const float4* wrx = (const float4*)(Wip + ((size_t)(g*128 + c)) * 64);
        const float4* wrz = (const float4*)(Wip + ((size_t)(g*128 + 64 + c)) * 64);
        #pragma unroll
        for(int j = 0; j < 16; j++){
            float4 u = wrx[j], v = wrz[j];
            wx[4*j]=u.x; wx[4*j+1]=u.y; wx[4*j+2]=u.z; wx[4*j+3]=u.w;
            wz[4*j]=v.x; wz[4*j+1]=v.y; wz[4*j+2]=v.z; wz[4*j+3]=v.w;
        }
    }
    float wsx = wsip[g*128 + c],      cvx = cvip[g*128 + c];
    float wsz = wsip[g*128 + 64 + c], cvz = cvip[g*128 + 64 + c];
    size_t row0 = (size_t)b * NN + n0 + q*32;
    unsigned long long xa0 = rfl64(x + row0 * CC + g*64);
    unsigned long long ma0 = rfl64(mrs + 2 * row0);
    size_t obase = ((size_t)(b*4 + g)) * NN + n0 + q*32;
    for(int l = 0; l < 32; l++){
        unsigned long long xa = xa0 + (unsigned long long)l * (CC*4);
        unsigned long long ma = ma0 + (unsigned long long)l * 8;
        f32x16 x0, x1, x2, x3; f32x2 mv;
        // single asm: loads + waitcnt together -> consumers are data-dependent
        // on outputs (no rule-18 hoisting hazard). SMEM needs lgkmcnt(0).
        asm volatile(
            "s_load_dwordx16 %0, %5, 0x0\n\t"
            "s_load_dwordx16 %1, %5, 0x40\n\t"
            "s_load_dwordx16 %2, %5, 0x80\n\t"
            "s_load_dwordx16 %3, %5, 0xc0\n\t"
            "s_load_dwordx2  %4, %6, 0x0\n\t"
            "s_waitcnt lgkmcnt(0)"
            : "=s"(x0), "=s"(x1), "=s"(x2), "=s"(x3), "=s"(mv)
            : "s"(xa), "s"(ma));
        float ax0 = 0.f, ax1 = 0.f, az0 = 0.f, az1 = 0.f;
        #pragma unroll
        for(int k = 0; k < 16; k++){
            ax0 += x0[k]*wx[k];     az0 += x0[k]*wz[k];
            ax1 += x1[k]*wx[16+k];  az1 += x1[k]*wz[16+k];
        }
        #pragma unroll
        for(int k = 0; k < 16; k++){
            ax0 += x2[k]*wx[32+k];  az0 += x2[k]*wz[32+k];
            ax1 += x3[k]*wx[48+k];  az1 += x3[k]*wz[48+k];
        }
        float m = mv[0], rv = mv[1];
        float ax = ax0 + ax1, az = az0 + az1;
        float vx = rv*ax - m*rv*wsx + cvx;
        float vz = rv*az - m*rv*wsz + cvz;
        xib [(obase + l)*64 + c] = vx;
        zbuf[(obase + l)*64 + c] = vz * sigmf(vz);
    }
}

// ------ K4a (tier3 fallback): LN + full in_proj per 128-pos tile -----------------
__global__ __launch_bounds__(256) void k_inproj(const float* __restrict__ x,
        const float* __restrict__ mrs, const float* __restrict__ nw,
        const float* __restrict__ nb, const float* __restrict__ ipw,
        const float* __restrict__ ipb, float* __restrict__ xib,
        float* __restrict__ zbuf){
    int tile = blockIdx.x, b = blockIdx.y, g = blockIdx.z;
    int n0 = tile * 128;
    __shared__ float xs[128 * 64];
    int tid = threadIdx.x;
    for(int idx = tid; idx < 2048; idx += 256){
        int p = idx >> 4, k4 = (idx & 15) * 4;
        size_t r = (size_t)b * NN + n0 + p;
        float4 v = *(const float4*)(x + r * CC + g*64 + k4);
        float m = mrs[2*r], rs = mrs[2*r+1];
        float4 w4 = *(const float4*)(nw + g*64 + k4);
        float4 b4 = *(const float4*)(nb + g*64 + k4);
        float4 o;
        o.x = (v.x - m)*rs*w4.x + b4.x;
        o.y = (v.y - m)*rs*w4.y + b4.y;
        o.z = (v.z - m)*rs*w4.z + b4.z;
        o.w = (v.w - m)*rs*w4.w + b4.w;
        *(float4*)(xs + p*64 + k4) = o;
    }
    __syncthreads();
    int c = tid & 63, ph = tid >> 6;
    float wx[64], wz[64];
    {
        const float* wrx = ipw + ((size_t)(g*128 + c)) * 64;
        const float* wrz = ipw + ((size_t)(g*128 + 64 + c)) * 64;
        #pragma unroll
        for(int k = 0; k < 64; k++){ wx[k] = wrx[k]; wz[k] = wrz[k]; }
    }
    float bx = ipb[g*128 + c], bz = ipb[g*128 + 64 + c];
    size_t obase = ((size_t)(b*4 + g)) * NN + n0;
    for(int p = ph*32; p < ph*32 + 32; p++){
        const float4* xp = (const float4*)(xs + p*64);
        float a0 = 0.f, a1 = 0.f, z0 = 0.f, z1 = 0.f;
        #pragma unroll
        for(int k4 = 0; k4 < 16; k4 += 2){
            float4 u = xp[k4], v = xp[k4+1];
            a0 += u.x*wx[4*k4+0]; a1 += u.y*wx[4*k4+1];
            a0 += u.z*wx[4*k4+2]; a1 += u.w*wx[4*k4+3];
            z0 += u.x*wz[4*k4+0]; z1 += u.y*wz[4*k4+1];
            z0 += u.z*wz[4*k4+2]; z1 += u.w*wz[4*k4+3];
            a0 += v.x*wx[4*k4+4]; a1 += v.y*wx[4*k4+5];
            a0 += v.z*wx[4*k4+6]; a1 += v.w*wx[4*k4+7];
            z0 += v.x*wz[4*k4+4]; z1 += v.y*wz[4*k4+5];
            z0 += v.z*wz[4*k4+6]; z1 += v.w*wz[4*k4+7];
        }
        float xv = bx + a0 + a1;
        float zv = bz + z0 + z1;
        xib[(obase + p)*64 + c] = xv;
        zbuf[(obase + p)*64 + c] = zv * sigmf(zv);
    }
}

// ------ K4b: depthwise conv3x3 + silu, halo from global xi -----------------------
__global__ __launch_bounds__(256) void k_conv(const float* __restrict__ xib,
        const float* __restrict__ cw, const float* __restrict__ cb,
        float* __restrict__ out){
    int tile = blockIdx.x, b = blockIdx.y, g = blockIdx.z;
    int h0 = (tile/12)*8, w0 = (tile%12)*8;
    __shared__ float xs[100*64];
    int tid = threadIdx.x;
    size_t ibase = ((size_t)(b*4+g)) * NN;
    for(int i = tid; i < 6400; i += 256){
        int p = i >> 6, k = i & 63;
        int ph = h0 + p/10 - 1, pw = w0 + p%10 - 1;
        float v = 0.f;
        if(ph >= 0 && ph < HH && pw >= 0 && pw < WWI)
            v = xib[(ibase + (size_t)(ph*WWI + pw))*64 + k];
        xs[i] = v;
    }
    __syncthreads();
    int c = tid & 63, q = tid >> 6;
    float wk[9];
    const float* wp = cw + ((size_t)(g*64 + c))*9;
    #pragma unroll
    for(int j = 0; j < 9; j++) wk[j] = wp[j];
    float bias2 = cb[g*64 + c];
    for(int pi = q*16; pi < q*16+16; pi++){
        int py = pi >> 3, px = pi & 7;
        float acc = bias2;
        #pragma unroll
        for(int dy = 0; dy < 3; dy++)
            #pragma unroll
            for(int dx = 0; dx < 3; dx++)
                acc += xs[((py+dy)*10 + px+dx)*64 + c] * wk[dy*3+dx];
        float sv = acc * sigmf(acc);
        size_t r = (size_t)b*NN + (h0+py)*WWI + (w0+px);
        out[r*CC + g*64 + c] = sv;
    }
}

// ------ K4 (fallback): fused LN + in_proj(x half) + depthwise conv3x3 + silu -----
template<int ZPRE>
__global__ __launch_bounds__(256) void k_ipconv(const float* __restrict__ x,
        const float* __restrict__ mrs, const float* __restrict__ nw,
        const float* __restrict__ nb, const float* __restrict__ ipw,
        const float* __restrict__ ipb, const float* __restrict__ cw,
        const float* __restrict__ cb, float* __restrict__ out,
        float* __restrict__ zbuf){
    int tile = blockIdx.x, b = blockIdx.y, g = blockIdx.z;
    int h0 = (tile / 12) * 8, w0 = (tile % 12) * 8;
    __shared__ float xs[100 * 64];
    __shared__ float xi[100 * 64];
    int tid = threadIdx.x;
    for(int i = tid; i < 6400; i += 256){
        int p = i >> 6, k = i & 63;
        int ph = h0 + p / 10 - 1, pw = w0 + p % 10 - 1;
        float v = 0.f;
        if(ph >= 0 && ph < HH && pw >= 0 && pw < WWI){
            size_t r = (size_t)b * NN + ph * WWI + pw;
            v = (x[r * CC + g*64 + k] - mrs[2*r]) * mrs[2*r+1]
                * nw[g*64 + k] + nb[g*64 + k];
        }
        xs[i] = v;
    }
    __syncthreads();
    int c = tid & 63, q = tid >> 6;
    {
        float wv[64];
        const float* wr = ipw + ((size_t)(g * 128 + c)) * 64;
        #pragma unroll
        for(int k = 0; k < 64; k++) wv[k] = wr[k];
        float bias = ipb[g * 128 + c];
        for(int p = q * 25; p < q * 25 + 25; p++){
            int ph = h0 + p / 10 - 1, pw = w0 + p % 10 - 1;
            bool valid = (ph >= 0 && ph < HH && pw >= 0 && pw < WWI);
            float acc = bias;
            const float* xp = &xs[p * 64];
            #pragma unroll
            for(int k = 0; k < 64; k++) acc += xp[k] * wv[k];
            xi[p * 64 + c] = valid ? acc : 0.f;
        }
    }
    __syncthreads();
    float wk[9];
    const float* wp = cw + ((size_t)(g * 64 + c)) * 9;
    #pragma unroll
    for(int j = 0; j < 9; j++) wk[j] = wp[j];
    float bias2 = cb[g * 64 + c];
    for(int pi = q * 16; pi < q * 16 + 16; pi++){
        int py = pi >> 3, px = pi & 7;
        float acc = bias2;
        #pragma unroll
        for(int dy = 0; dy < 3; dy++)
            #pragma unroll
            for(int dx = 0; dx < 3; dx++)
                acc += xi[((py + dy) * 10 + px + dx) * 64 + c] * wk[dy*3 + dx];
        float sv = acc * sigmf(acc);
        size_t r = (size_t)b * NN + (h0 + py) * WWI + (w0 + px);
        out[r * CC + g*64 + c] = sv;
    }
    if(ZPRE){
        float wzv[64];
        const float* wr = ipw + ((size_t)(g * 128 + 64 + c)) * 64;
        #pragma unroll
        for(int k = 0; k < 64; k++) wzv[k] = wr[k];
        float zbv = ipb[g * 128 + 64 + c];
        size_t zb0 = ((size_t)(b * 4 + g)) * NN;
        for(int p16 = 0; p16 < 16; p16++){
            int p = q * 16 + p16;
            int py = p >> 3, px = p & 7;
            const float* xp = &xs[((py + 1) * 10 + (px + 1)) * 64];
            float acc = zbv;
            #pragma unroll
            for(int k = 0; k < 64; k++) acc += xp[k] * wzv[k];
            zbuf[(zb0 + (size_t)((h0 + py) * WWI + (w0 + px))) * 64 + c]
                = acc * sigmf(acc);
        }
    }
}

// ---------------- K5: scan phase 1 — on-the-fly xdbl, prod(a), h_end -------------
__global__ __launch_bounds__(64) void k_scan1(const float* __restrict__ out,
        const float* __restrict__ xpw, const float* __restrict__ dtw,
        const float* __restrict__ dtb, const float* __restrict__ alog,
        float* __restrict__ ap_out, float* __restrict__ h_out){
    int chunk = blockIdx.x, gb = blockIdx.y;
    int g = gb >> 3, b = gb & 7, d = threadIdx.x;
    __shared__ float s_seq[CHK * 65];
    __shared__ float s_xd[CHK * 6];
    __shared__ float s_w[6 * 64];
    int base, step; chunk_walk(g, chunk, base, step);
    const float* xg = out + (size_t)b * NN * CC + g * 64;
    for(int j = 0; j < CHK; j++)
        s_seq[j * 65 + d] = xg[(size_t)(base + j * step) * CC + d];
    for(int i = d; i < 384; i += 64) s_w[i] = xpw[g * 384 + i];
    __syncthreads();
    for(int idx = d; idx < CHK*6; idx += 64){
        int l = idx / 6, j = idx % 6;
        float acc = 0.f;
        const float* sr = &s_seq[l * 65];
        const float* wr = &s_w[j * 64];
        #pragma unroll
        for(int k = 0; k < 64; k++) acc += sr[k] * wr[k];
        s_xd[idx] = acc;
    }
    __syncthreads();
    int gd = g * 64 + d;
    float Av = -expf(alog[gd]);
    float db = dtb[gd];
    float w0 = dtw[gd*4], w1 = dtw[gd*4+1], w2 = dtw[gd*4+2], w3 = dtw[gd*4+3];
    float h = 0.f, apd = 1.f;
    #pragma unroll 4
    for(int l = 0; l < CHK; l++){
        const float* xd = &s_xd[l * 6];
        float xv = s_seq[l*65 + d];
        float dt = softplusf(xd[0]*w0 + xd[1]*w1 + xd[2]*w2 + xd[3]*w3 + db);
        float a = expf(dt * Av);
        h = a*h + dt*xv*xd[4];
        apd *= a;
    }
    int ob = (gb * NCH + chunk) * 64 + d;
    ap_out[ob] = apd; h_out[ob] = h;
}

// ---------------- K6: scan phase 2 — serial scan over chunk summaries ------------
__global__ __launch_bounds__(256) void k_scan2(const float* __restrict__ ap,
        const float* __restrict__ he, float* __restrict__ hinit){
    int idx = blockIdx.x * 256 + threadIdx.x;   // 0..2047
    int gb = idx >> 6, d = idx & 63;
    float h = 0.f;
    for(int c = 0; c < NCH; c++){
        int o = (gb * NCH + c) * 64 + d;
        hinit[o] = h;
        h = ap[o]*h + he[o];
    }
}

// --- K7: scan phase 3 + out_norm LN + silu(z) gate, IN PLACE ---------------------
template<int ZPRE>
__global__ __launch_bounds__(64) void k_scan3(float* __restrict__ out,
        const float* __restrict__ x, const float* __restrict__ mrs,
        const float* __restrict__ nw, const float* __restrict__ nb,
        const float* __restrict__ ipw, const float* __restrict__ ipb,
        const float* __restrict__ xpw, const float* __restrict__ dtw,
        const float* __restrict__ dtb, const float* __restrict__ alog,
        const float* __restrict__ Dsp, const float* __restrict__ onw,
        const float* __restrict__ onb, const float* __restrict__ hinit,
        const float* __restrict__ zbuf){
    int chunk = blockIdx.x, gb = blockIdx.y;
    int g = gb >> 3, b = gb & 7, d = threadIdx.x;
    __shared__ float s_seq[CHK * 65];          // seq, then y (overwritten in place)
    __shared__ float s_xd[CHK * 6];
    __shared__ float s_w[6 * 64];
    __shared__ float xnt[(ZPRE ? 1 : CHK) * 65];
    int base, step; chunk_walk(g, chunk, base, step);
    float* xg = out + (size_t)b * NN * CC + g * 64;
    for(int j = 0; j < CHK; j++)
        s_seq[j * 65 + d] = xg[(size_t)(base + j * step) * CC + d];
    if(!ZPRE){
        float nwv = nw[g*64 + d], nbv = nb[g*64 + d];
        for(int j = 0; j < CHK; j++){
            int n = base + j * step;
            size_t r = (size_t)b * NN + n;
            xnt[j * 65 + d] = (x[r * CC + g*64 + d] - mrs[2*r]) * mrs[2*r+1] * nwv + nbv;
        }
    }
    for(int i = d; i < 384; i += 64) s_w[i] = xpw[g * 384 + i];
    __syncthreads();
    for(int idx = d; idx < CHK*6; idx += 64){
        int l = idx / 6, j = idx % 6;
        float acc = 0.f;
        const float* sr = &s_seq[l * 65];
        const float* wr = &s_w[j * 64];
        #pragma unroll
        for(int k = 0; k < 64; k++) acc += sr[k] * wr[k];
        s_xd[idx] = acc;
    }
    __syncthreads();
    int gd = g * 64 + d;
    float Av = -expf(alog[gd]);
    float db = dtb[gd];
    float Dv = Dsp[gd];
    float w0 = dtw[gd*4], w1 = dtw[gd*4+1], w2 = dtw[gd*4+2], w3 = dtw[gd*4+3];
    float h = hinit[(gb * NCH + chunk) * 64 + d];
    // ---- Phase A: scan. Only h is loop-carried; y overwrites s_seq row. ----
    #pragma unroll 4
    for(int l = 0; l < CHK; l++){
        const float* xd = &s_xd[l * 6];
        float xv = s_seq[l*65 + d];
        float dt = softplusf(xd[0]*w0 + xd[1]*w1 + xd[2]*w2 + xd[3]*w3 + db);
        float a = expf(dt * Av);
        h = a*h + dt*xv*xd[4];
        s_seq[l*65 + d] = h * xd[5] + Dv * xv;
    }
    // ---- Phase B: out_norm LN + silu(z) gate. Iterations independent. ----
    float wON = onw[gd], bON = onb[gd];
    float wz[ZPRE ? 1 : 64];
    float zb = 0.f;
    if(!ZPRE){
        const float* wr = ipw + ((size_t)(g * 128 + 64 + d)) * 64;
        #pragma unroll
        for(int k = 0; k < 64; k++) wz[k] = wr[k];
        zb = ipb[g * 128 + 64 + d];
    }
    const float* zp = zbuf + (((size_t)(b * 4 + g)) * NN) * 64 + d;
    #pragma unroll 4
    for(int l = 0; l < CHK; l++){
        float y = s_seq[l*65 + d];
        float s = y, q = y * y;
        wredsum2(s, q);
        float m = s * (1.f/64.f);
        float var = q * (1.f/64.f) - m*m;
        float rs = rsqrtf(fmaxf(var, 0.f) + 1e-5f);
        float lny = (y - m) * rs * wON + bON;
        int n = base + l * step;
        float zs;
        if(ZPRE){
            zs = zp[(size_t)n * 64];
        } else {
            float z = zb;
            const float* xp = &xnt[l * 65];
            #pragma unroll
            for(int k = 0; k < 64; k++) z += xp[k] * wz[k];
            zs = z * sigmf(z);
        }
        xg[(size_t)n * CC + d] = lny * zs;   // in-place (own tile)
    }
}

// --- K8 (fallback): out_proj + skip*xn*gate, spatial tiles, IN PLACE -------------
__global__ __launch_bounds__(64) void k_out2(float* __restrict__ out,
        const float* __restrict__ x, const float* __restrict__ mrs,
        const float* __restrict__ nw, const float* __restrict__ nb,
        const float* __restrict__ opw, const float* __restrict__ opb,
        const float* __restrict__ gate, const float* __restrict__ skip){
    int tile = blockIdx.x, b = blockIdx.y, g = blockIdx.z;
    int n0 = tile * 64, t = threadIdx.x;
    __shared__ float ly[64 * 65];
    __shared__ float xnt[64 * 65];
    float* xg = out + (size_t)b * NN * CC + g * 64;
    float nwv = nw[g*64 + t], nbv = nb[g*64 + t];
    for(int p = 0; p < 64; p++){
        size_t r = (size_t)b * NN + n0 + p;
        ly[p * 65 + t] = xg[(size_t)(n0 + p) * CC + t];
        xnt[p * 65 + t] = (x[r * CC + g*64 + t] - mrs[2*r]) * mrs[2*r+1] * nwv + nbv;
    }
    __syncthreads();
    float wv[64];
    const float* wr = opw + ((size_t)(g * 64 + t)) * 64;
    #pragma unroll
    for(int k = 0; k < 64; k++) wv[k] = wr[k];
    float bias = opb[g * 64 + t];
    float gv = gate[b * CC + g*64 + t];
    float sk = skip[0];
    for(int p = 0; p < 64; p++){
        float acc = bias;
        const float* yp = &ly[p * 65];
        #pragma unroll
        for(int k = 0; k < 64; k++) acc += yp[k] * wv[k];
        xg[(size_t)(n0 + p) * CC + t] = acc * sk * xnt[p * 65 + t] * gv;
    }
}

// --- K8new: out_proj + skip*xn*gate + fused row-stats, LDS-free ------------------
__global__ __launch_bounds__(256) void k_out3(const float* __restrict__ yin,
        const float* __restrict__ x, const float* __restrict__ mrs,
        const float* __restrict__ nw, const float* __restrict__ nb,
        const float* __restrict__ opw, const float* __restrict__ opb,
        const float* __restrict__ gate, const float* __restrict__ skip,
        float* __restrict__ zo, float* __restrict__ mrs2){
    __shared__ float ps[16 * 4], pq[16 * 4];
    int o = threadIdx.x;
    int g = o >> 6, c = o & 63;
    int r0 = blockIdx.x * 16;           // 16 rows/block; NN%16==0 -> same b
    int b  = r0 / NN;
    int n0 = r0 - b * NN;
    float wv[64];
    {
        const float4* wr = (const float4*)(opw + ((size_t)(g*64 + c)) * 64);
        #pragma unroll
        for(int j = 0; j < 16; j++){
            float4 t4 = wr[j];
            wv[4*j+0] = t4.x; wv[4*j+1] = t4.y;
            wv[4*j+2] = t4.z; wv[4*j+3] = t4.w;
        }
    }
    float acc[16];
    const float* ab = yin + ((size_t)b * NN + n0) * CC + g * 64;
    #pragma unroll 4
    for(int r = 0; r < 16; r++){
        const float4* ar = (const float4*)(ab + (size_t)r * CC);  // wave-uniform
        float s0 = 0.f, s1 = 0.f;
        #pragma unroll
        for(int j = 0; j < 8; j++){
            float4 u = ar[j], v = ar[j + 8];
            s0 += u.x*wv[4*j+0]  + u.y*wv[4*j+1]  + u.z*wv[4*j+2]  + u.w*wv[4*j+3];
            s1 += v.x*wv[32+4*j] + v.y*wv[33+4*j] + v.z*wv[34+4*j] + v.w*wv[35+4*j];
        }
        acc[r] = s0 + s1;
    }
    float bias = opb[g*64 + c];
    float gv = gate[b * CC + g*64 + c];
    float sk = skip[0];
    float nwv = nw[g*64 + c], nbv = nb[g*64 + c];
    size_t zbase = ((size_t)(b*4 + g)) * NN + n0;
    #pragma unroll
    for(int r = 0; r < 16; r++){
        size_t row = (size_t)r0 + r;
        float xv = x[row * CC + g*64 + c];           // per-lane coalesced
        float xn = (xv - mrs[2*row]) * mrs[2*row+1] * nwv + nbv;
        float res = (acc[r] + bias) * sk * xn * gv;
        acc[r] = res;
        zo[(zbase + r) * 64 + c] = res;
    }
    // fused row stats over 256 channels (64 lanes x 4 waves)
    #pragma unroll
    for(int r = 0; r < 16; r++){
        float s = acc[r], q = acc[r] * acc[r];
        wredsum2(s, q);
        if(c == 0){ ps[r*4 + g] = s; pq[r*4 + g] = q; }
    }
    __syncthreads();
    if(o < 16){
        float ss = ps[o*4] + ps[o*4+1] + ps[o*4+2] + ps[o*4+3];
        float qq = pq[o*4] + pq[o*4+1] + pq[o*4+2] + pq[o*4+3];
        float m = ss * (1.f/256.f);
        float var = qq * (1.f/256.f) - m*m;
        mrs2[2*((size_t)r0 + o)]     = m;
        mrs2[2*((size_t)r0 + o) + 1] = rsqrtf(fmaxf(var, 0.f) + 1e-5f);
    }
}

// ---------------- K9 (fallback): final LN + proj GEMM, IN PLACE ------------------
__global__ __launch_bounds__(256) void k_final(float* __restrict__ out,
        const float* __restrict__ nw, const float* __restrict__ nb,
        const float* __restrict__ pw, const float* __restrict__ pb){
    __shared__ float A[16 * 256];
    __shared__ float ps[256], pq[256];
    __shared__ float mrow[16], rrow[16];
    int n0 = blockIdx.x * 16;
    for(int i = threadIdx.x; i < 4096; i += 256)
        A[i] = out[(size_t)n0 * CC + i];
    __syncthreads();
    {
        int r = threadIdx.x >> 4, t16 = threadIdx.x & 15;
        float s = 0.f, q = 0.f;
        for(int j = 0; j < 16; j++){
            float v = A[r*256 + t16*16 + j];
            s += v; q += v*v;
        }
        ps[threadIdx.x] = s; pq[threadIdx.x] = q;
    }
    __syncthreads();
    if(threadIdx.x < 16){
        float ss = 0.f, qq = 0.f;
        for(int j = 0; j < 16; j++){ ss += ps[threadIdx.x*16 + j]; qq += pq[threadIdx.x*16 + j]; }
        float m = ss * (1.f/256.f);
        float var = qq * (1.f/256.f) - m*m;
        mrow[threadIdx.x] = m;
        rrow[threadIdx.x] = rsqrtf(fmaxf(var, 0.f) + 1e-5f);
    }
    __syncthreads();
    for(int i = threadIdx.x; i < 4096; i += 256){
        int r = i >> 8, c = i & 255;
        A[i] = (A[i] - mrow[r]) * rrow[r] * nw[c] + nb[c];
    }
    __syncthreads();
    int o = threadIdx.x;
    float acc[16];
    #pragma unroll
    for(int p = 0; p < 16; p++) acc[p] = 0.f;
    for(int kt = 0; kt < 4; kt++){
        float wv[64];
        const float4* wr = (const float4*)(pw + (size_t)o * CC + kt * 64);
        #pragma unroll
        for(int j = 0; j < 16; j++){
            float4 tq = wr[j];
            wv[4*j+0] = tq.x; wv[4*j+1] = tq.y;
            wv[4*j+2] = tq.z; wv[4*j+3] = tq.w;
        }
        #pragma unroll
        for(int p = 0; p < 16; p++){
            const float* ar = &A[p*256 + kt*64];
            float a = 0.f;
            #pragma unroll
            for(int k = 0; k < 64; k++) a += ar[k] * wv[k];
            acc[p] += a;
        }
    }
    float pbv = pb[o];
    #pragma unroll
    for(int p = 0; p < 16; p++)
        out[(size_t)(n0 + p) * CC + o] = acc[p] + pbv;
}

// ---------------- K9new: LN-folded proj GEMM, LDS-free ---------------------------
__global__ __launch_bounds__(256) void k_final2(const float* __restrict__ y,
        const float* __restrict__ mrs2, const float* __restrict__ Wn,
        const float* __restrict__ wsum, const float* __restrict__ cvec,
        float* __restrict__ out){
    int o = threadIdx.x;
    int r0 = blockIdx.x * 16;           // global row base (16 rows/block)
    int b  = r0 / NN;
    int n0 = r0 - b * NN;               // NN divisible by 16: all rows same b
    float acc[16];
    #pragma unroll
    for(int r = 0; r < 16; r++) acc[r] = 0.f;
    for(int kt = 0; kt < 4; kt++){
        float wv[64];
        const float4* wr = (const float4*)(Wn + (size_t)o * 256 + kt * 64);
        #pragma unroll
        for(int j = 0; j < 16; j++){
            float4 t4 = wr[j];
            wv[4*j+0] = t4.x; wv[4*j+1] = t4.y;
            wv[4*j+2] = t4.z; wv[4*j+3] = t4.w;
        }
        const float* ab = y + ((size_t)(b*4 + kt)*NN + n0) * 64;
        #pragma unroll 4
        for(int r = 0; r < 16; r++){
            const float* ar = ab + (size_t)r * 64;   // wave-uniform address
            float s0 = 0.f, s1 = 0.f;
            #pragma unroll
            for(int j = 0; j < 32; j++){
                s0 += ar[j]      * wv[j];
                s1 += ar[j + 32] * wv[j + 32];
            }
            acc[r] += s0 + s1;
        }
    }
    float wso = wsum[o], co = cvec[o];
    #pragma unroll
    for(int r = 0; r < 16; r++){
        float m  = mrs2[2*(size_t)(r0 + r)];
        float rs = mrs2[2*(size_t)(r0 + r) + 1];
        out[(size_t)(r0 + r) * CC + o] = rs * acc[r] - m * rs * wso + co;
    }
}

extern "C" void kernel_launch(void* const* d_in, const int* in_sizes, int n_in,
                              void* d_out, int out_size, void* d_ws, size_t ws_size,
                              hipStream_t stream){
    const float* x    = (const float*)d_in[0];
    const float* nw   = (const float*)d_in[1];
    const float* nb   = (const float*)d_in[2];
    const float* fcw  = (const float*)d_in[3];
    const float* fcb  = (const float*)d_in[4];
    const float* w1d  = (const float*)d_in[5];
    const float* ipw  = (const float*)d_in[6];
    const float* ipb  = (const float*)d_in[7];
    const float* cw   = (const float*)d_in[8];
    const float* cb   = (const float*)d_in[9];
    const float* xpw  = (const float*)d_in[10];
    const float* dtw  = (const float*)d_in[11];
    const float* dtb  = (const float*)d_in[12];
    const float* alog = (const float*)d_in[13];
    const float* Dsp  = (const float*)d_in[14];
    const float* onw  = (const float*)d_in[15];
    const float* onb  = (const float*)d_in[16];
    const float* opw  = (const float*)d_in[17];
    const float* opb  = (const float*)d_in[18];
    const float* pw   = (const float*)d_in[19];
    const float* pb   = (const float*)d_in[20];
    const float* skip = (const float*)d_in[21];

    // Workspace layout:
    //   base 2,957,312 | zbuf 75,497,472 | mrs2 589,824 | Wn 262,144
    //   | wsum 1,024 | cvec 1,024   -> T2 = 79,308,800
    //   | xib 75,497,472            -> T3 = 154,806,272
    //   | Wip 131,072 | wsip 2,048 | cvip 2,048 -> T4 = 154,941,440
    char* base = (char*)d_ws;
    float* mrs  = (float*)base;                      //   589,824 B
    float* gate = (float*)(base +  589824ull);       //     8,192 B
    float* ap   = (float*)(base +  598016ull);       //   786,432 B (zpart aliases)
    float* he   = (float*)(base + 1384448ull);       //   786,432 B
    float* hi   = (float*)(base + 2170880ull);       //   786,432 B
    float* zbuf = (float*)(base + 2957312ull);       //  75,497,472 B
    float* mrs2 = (float*)(base + 78454784ull);      //   589,824 B
    float* Wn   = (float*)(base + 79044608ull);      //   262,144 B
    float* wsum = (float*)(base + 79306752ull);      //     1,024 B
    float* cvec = (float*)(base + 79307776ull);      //     1,024 B
    float* xib  = (float*)(base + 79308800ull);      //  75,497,472 B
    float* Wip  = (float*)(base + 154806272ull);     //   131,072 B
    float* wsip = (float*)(base + 154937344ull);     //     2,048 B
    float* cvip = (float*)(base + 154939392ull);     //     2,048 B
    float* zpart = ap;                               // dead before k_scan1 writes ap
    float* out  = (float*)d_out;                     // spatial (B,N,256) scratch
    (void)in_sizes; (void)n_in; (void)out_size;

    const size_t T1 = 78454784ull;    // base + zbuf
    const size_t T2 = 79308800ull;    // + mrs2 + Wn + wsum + cvec
    const size_t T3 = 154806272ull;   // + xib
    const size_t T4 = 154941440ull;   // + Wip + wsip + cvip
    bool usez    = ws_size >= T1;
    bool usef2   = ws_size >= T2;
    bool usesplit= ws_size >= T3;
    bool useip3  = ws_size >= T4;

    if(usef2)
        k_prew<<<1, 256, 0, stream>>>(pw, nw, nb, pb, Wn, wsum, cvec);
    if(useip3)
        k_prewip<<<4, 128, 0, stream>>>(ipw, nw, nb, ipb, Wip, wsip, cvip);
    k_stats <<<18432, 256, 0, stream>>>(x, mrs);
    k_zavg  <<<dim3(36, 8), 256, 0, stream>>>(x, mrs, nw, nb, zpart);
    k_gate  <<<8, 256, 0, stream>>>(zpart, fcw, fcb, w1d, gate);
    if(useip3){
        k_inproj3<<<dim3(72, 8, 4), 256, 0, stream>>>(x, mrs, Wip, wsip, cvip,
                                                      xib, zbuf);
        k_conv  <<<dim3(144, 8, 4), 256, 0, stream>>>(xib, cw, cb, out);
    } else if(usesplit){
        k_inproj<<<dim3(72, 8, 4), 256, 0, stream>>>(x, mrs, nw, nb, ipw, ipb,
                                                     xib, zbuf);
        k_conv  <<<dim3(144, 8, 4), 256, 0, stream>>>(xib, cw, cb, out);
    } else if(usez){
        k_ipconv<1><<<dim3(144, 8, 4), 256, 0, stream>>>(x, mrs, nw, nb, ipw, ipb,
                                                         cw, cb, out, zbuf);
    } else {
        k_ipconv<0><<<dim3(144, 8, 4), 256, 0, stream>>>(x, mrs, nw, nb, ipw, ipb,
                                                         cw, cb, out, zbuf);
    }
    k_scan1 <<<dim3(96, 32), 64, 0, stream>>>(out, xpw, dtw, dtb, alog, ap, he);
    k_scan2 <<<8, 256, 0, stream>>>(ap, he, hi);
    if(usez){
        k_scan3<1><<<dim3(96, 32), 64, 0, stream>>>(out, x, mrs, nw, nb, ipw, ipb,
                                                    xpw, dtw, dtb, alog, Dsp, onw,
                                                    onb, hi, zbuf);
    } else {
        k_scan3<0><<<dim3(96, 32), 64, 0, stream>>>(out, x, mrs, nw, nb, ipw, ipb,
                                                    xpw, dtw, dtb, alog, Dsp, onw,
                                                    onb, hi, zbuf);
    }
    if(usef2){
        k_out3  <<<4608, 256, 0, stream>>>(out, x, mrs, nw, nb, opw, opb,
                                           gate, skip, zbuf, mrs2);
        k_final2<<<4608, 256, 0, stream>>>(zbuf, mrs2, Wn, wsum, cvec, out);
    } else {
        k_out2  <<<dim3(144, 8, 4), 64, 0, stream>>>(out, x, mrs, nw, nb, opw, opb,
                                                     gate, skip);
        k_final <<<4608, 256, 0, stream>>>(out, nw, nb, pw, pb);
    }
}